// Round 10
// baseline (1802.314 us; speedup 1.0000x reference)
//
#include <hip/hip_runtime.h>
#include <stdint.h>

#define TSTEPS 50
#define BATCH  1024
#define INDIM  405
#define KP     448      // padded K for gx GEMM (7 x 64)
#define HDIM   200
#define G4H    800      // 4*H
#define NMEM   128
#define DMEM   40
#define DPAD   44       // sM row stride: 16B-aligned
#define RH     4
#define RD     160      // RH*DMEM
#define NWAY   5
#define GAMMA_ 0.99f
#define NG     2        // batches per block; 512 blocks, 512 thr -> 2 blocks/CU
#define WROWS  928      // gx GEMM W rows padded

typedef __attribute__((ext_vector_type(8))) short short8;
typedef __attribute__((ext_vector_type(4))) float f32x4;

__device__ __forceinline__ float sigmoidf_(float x) {
    return 1.f / (1.f + __expf(-x));
}
__device__ __forceinline__ float ftanh(float x) {
    float e = __expf(2.f * x);
    return 1.f - 2.f / (e + 1.f);
}
__device__ __forceinline__ unsigned short f2bf(float f) {   // RNE f32->bf16
    uint32_t u = __float_as_uint(f);
    uint32_t r = u + 0x7FFFu + ((u >> 16) & 1u);
    return (unsigned short)(r >> 16);
}
__device__ __forceinline__ float bf2f(unsigned short h) {
    return __uint_as_float(((uint32_t)h) << 16);
}
__device__ __forceinline__ float bflo(uint32_t u) { return __uint_as_float(u << 16); }
__device__ __forceinline__ float bfhi(uint32_t u) { return __uint_as_float(u & 0xFFFF0000u); }

// ---- quad-pack recurrent weights (round-8 layout) --------------------------
__global__ __launch_bounds__(256) void convert_recQ(const float* __restrict__ W_hh,
                                                    const float* __restrict__ Wk,
                                                    uint4* __restrict__ Whh_q4,
                                                    uint2* __restrict__ Wk_q2) {
    int i = blockIdx.x * 256 + threadIdx.x;
    if (i < 50 * 400) {
        int jq = i / 400, p = i % 400;
        int j = jq * 4;
        const float* r0 = W_hh + (2 * p) * HDIM;
        const float* r1 = W_hh + (2 * p + 1) * HDIM;
        uint4 v;
        v.x = (uint32_t)f2bf(r0[j])     | ((uint32_t)f2bf(r0[j + 1]) << 16);
        v.y = (uint32_t)f2bf(r1[j])     | ((uint32_t)f2bf(r1[j + 1]) << 16);
        v.z = (uint32_t)f2bf(r0[j + 2]) | ((uint32_t)f2bf(r0[j + 3]) << 16);
        v.w = (uint32_t)f2bf(r1[j + 2]) | ((uint32_t)f2bf(r1[j + 3]) << 16);
        Whh_q4[i] = v;
    } else if (i < 50 * 400 + 50 * 160) {
        int e = i - 50 * 400;
        int jq = e / 160, col = e % 160;
        int j = jq * 4;
        const float* r = Wk + col * HDIM;
        uint2 v;
        v.x = (uint32_t)f2bf(r[j])     | ((uint32_t)f2bf(r[j + 1]) << 16);
        v.y = (uint32_t)f2bf(r[j + 2]) | ((uint32_t)f2bf(r[j + 3]) << 16);
        Wk_q2[e] = v;
    }
}

// ---------------- split f32 -> (hi, lo) bf16, zero-padded K (gx GEMM) ------
__global__ __launch_bounds__(256) void convert_A(const float* __restrict__ x,
                                                 unsigned short* __restrict__ Ahi,
                                                 unsigned short* __restrict__ Alo) {
    int c = blockIdx.x * 256 + threadIdx.x;
    int r = blockIdx.y;
    if (c >= KP) return;
    float v = (c < INDIM) ? x[(size_t)r * INDIM + c] : 0.f;
    unsigned short hi = f2bf(v);
    unsigned short lo = f2bf(v - bf2f(hi));
    size_t o = (size_t)r * KP + c;
    Ahi[o] = hi;
    Alo[o] = lo;
}

__global__ __launch_bounds__(256) void convert_W(const float* __restrict__ W_ih,
                                                 unsigned short* __restrict__ Wpk) {
    int c = blockIdx.x * 256 + threadIdx.x;
    int n = blockIdx.y;
    int sec = blockIdx.z;
    if (c >= KP) return;
    float v = (n < G4H && c < INDIM) ? W_ih[(size_t)n * INDIM + c] : 0.f;
    unsigned short hi = f2bf(v);
    size_t o = (size_t)sec * WROWS * KP + (size_t)n * KP + c;
    Wpk[o] = (sec == 0) ? hi : f2bf(v - bf2f(hi));
}

// ---------------- gx GEMM via 3-term split-bf16 MFMA ----------------------
__global__ __launch_bounds__(256) void gx_gemm_mfma(
        const unsigned short* __restrict__ Ahi,
        const unsigned short* __restrict__ Alo,
        const unsigned short* __restrict__ Wpk,
        const float* __restrict__ b_ih, const float* __restrict__ b_hh,
        float* __restrict__ gx) {
    __shared__ unsigned short Alds[128 * 64];
    __shared__ unsigned short Blds[128 * 64];
    const int tid = threadIdx.x;
    const int wv = tid >> 6, ln = tid & 63;
    const int wr = wv >> 1, wc = wv & 1;
    const int n0 = blockIdx.x * 128;
    const int m0 = blockIdx.y * 128;

    f32x4 acc[4][4];
#pragma unroll
    for (int m = 0; m < 4; ++m)
#pragma unroll
        for (int n = 0; n < 4; ++n) acc[m][n] = (f32x4){0.f, 0.f, 0.f, 0.f};

    int erow[4], ecol[4];
#pragma unroll
    for (int i = 0; i < 4; ++i) {
        int e = (i * 4 + wv) * 512 + ln * 8;
        erow[i] = e >> 6;
        ecol[i] = e & 63;
    }

    const unsigned short* Whi = Wpk;
    const unsigned short* Wlo = Wpk + (size_t)WROWS * KP;

#pragma unroll 1
    for (int s = 0; s < 3; ++s) {
        const unsigned short* Ab = ((s == 2) ? Alo : Ahi) + (size_t)m0 * KP;
        const unsigned short* Bb = ((s == 1) ? Wlo : Whi) + (size_t)n0 * KP;

        short8 ar[4], br[4];
#pragma unroll
        for (int i = 0; i < 4; ++i) {
            ar[i] = *(const short8*)&Ab[(size_t)erow[i] * KP + ecol[i]];
            br[i] = *(const short8*)&Bb[(size_t)erow[i] * KP + ecol[i]];
        }

#pragma unroll 1
        for (int k0 = 0; k0 < KP; k0 += 64) {
            __syncthreads();
#pragma unroll
            for (int i = 0; i < 4; ++i) {
                int e = (i * 4 + wv) * 512 + ln * 8;
                *(short8*)&Alds[e] = ar[i];
                *(short8*)&Blds[e] = br[i];
            }
            __syncthreads();
            if (k0 + 64 < KP) {
#pragma unroll
                for (int i = 0; i < 4; ++i) {
                    ar[i] = *(const short8*)&Ab[(size_t)erow[i] * KP + k0 + 64 + ecol[i]];
                    br[i] = *(const short8*)&Bb[(size_t)erow[i] * KP + k0 + 64 + ecol[i]];
                }
            }
#pragma unroll
            for (int ks = 0; ks < 2; ++ks) {
                short8 af[4], bf[4];
                int kcol = ks * 32 + (ln >> 4) * 8;
#pragma unroll
                for (int m = 0; m < 4; ++m) {
                    int row = wr * 64 + m * 16 + (ln & 15);
                    af[m] = *(const short8*)&Alds[row * 64 + kcol];
                }
#pragma unroll
                for (int n = 0; n < 4; ++n) {
                    int row = wc * 64 + n * 16 + (ln & 15);
                    bf[n] = *(const short8*)&Blds[row * 64 + kcol];
                }
#pragma unroll
                for (int m = 0; m < 4; ++m)
#pragma unroll
                    for (int n = 0; n < 4; ++n)
                        acc[m][n] = __builtin_amdgcn_mfma_f32_16x16x32_bf16(
                            af[m], bf[n], acc[m][n], 0, 0, 0);
            }
        }
    }

#pragma unroll
    for (int n = 0; n < 4; ++n) {
        int col = n0 + wc * 64 + n * 16 + (ln & 15);
        if (col >= G4H) continue;
        float bias = b_ih[col] + b_hh[col];
#pragma unroll
        for (int m = 0; m < 4; ++m) {
#pragma unroll
            for (int j = 0; j < 4; ++j) {
                int row = m0 + wr * 64 + m * 16 + (ln >> 4) * 4 + j;
                gx[(size_t)row * G4H + col] = acc[m][n][j] + bias;
            }
        }
    }
}

// ---------------- f32 fallback GEMM ---------------------------------------
__global__ __launch_bounds__(256) void gx_gemm(const float* __restrict__ x,
                                               const float* __restrict__ W_ih,
                                               const float* __restrict__ b_ih,
                                               const float* __restrict__ b_hh,
                                               float* __restrict__ gx) {
    const int BM = 128, BN = 80, BK = 16;
    __shared__ float As[BK][BM];
    __shared__ float Bs[BK][BN];
    int m0 = blockIdx.y * BM;
    int n0 = blockIdx.x * BN;
    int tid = threadIdx.x;
    int tm = tid >> 4, tn = tid & 15;
    float acc[8][5];
#pragma unroll
    for (int i = 0; i < 8; ++i)
#pragma unroll
        for (int j = 0; j < 5; ++j) acc[i][j] = 0.f;

    for (int k0 = 0; k0 < INDIM; k0 += BK) {
        {
            int row = tid >> 1, kk = (tid & 1) * 8;
            const float* ap = x + (size_t)(m0 + row) * INDIM + k0 + kk;
#pragma unroll
            for (int i = 0; i < 8; ++i)
                As[kk + i][row] = (k0 + kk + i < INDIM) ? ap[i] : 0.f;
        }
        if (tid < 160) {
            int col = tid >> 1, kk = (tid & 1) * 8;
            const float* bp = W_ih + (size_t)(n0 + col) * INDIM + k0 + kk;
#pragma unroll
            for (int i = 0; i < 8; ++i)
                Bs[kk + i][col] = (k0 + kk + i < INDIM) ? bp[i] : 0.f;
        }
        __syncthreads();
#pragma unroll
        for (int k = 0; k < BK; ++k) {
            float a[8], b[5];
#pragma unroll
            for (int i = 0; i < 8; ++i) a[i] = As[k][tm * 8 + i];
#pragma unroll
            for (int j = 0; j < 5; ++j) b[j] = Bs[k][tn * 5 + j];
#pragma unroll
            for (int i = 0; i < 8; ++i)
#pragma unroll
                for (int j = 0; j < 5; ++j) acc[i][j] += a[i] * b[j];
        }
        __syncthreads();
    }
#pragma unroll
    for (int j = 0; j < 5; ++j) {
        int n = n0 + tn * 5 + j;
        float bias = b_ih[n] + b_hh[n];
#pragma unroll
        for (int i = 0; i < 8; ++i) {
            int m = m0 + tm * 8 + i;
            gx[(size_t)m * G4H + n] = acc[i][j] + bias;
        }
    }
}

// ---------------- persistent NTM scan: NG=2, 512 thr, 7 barriers/step ------
__global__ __launch_bounds__(512, 4) void ntm_scan(
        const float* __restrict__ gx,          // [T][B][800]
        const uint4* __restrict__ Whh_q4,      // [50][400] quad-packed bf16
        const uint2* __restrict__ Wk_q2,       // [50][160] quad-packed bf16
        const float* __restrict__ bk,
        const float* __restrict__ Wsm,         // [4][200]
        const float* __restrict__ bs,
        const float* __restrict__ Wo,          // [5][360]
        const float* __restrict__ bo,
        float* __restrict__ out) {             // [T][B][5]
    __shared__ float sM[NG][NMEM][DPAD];
    __shared__ float sh[NG][HDIM];
    __shared__ float sgate[NG][G4H];
    __shared__ float spartK[NG][2][RD];
    __shared__ float spartS[NG][RH][4];
    __shared__ float swr[NG][RH][NMEM];
    __shared__ float sww[NG][RH][NMEM];
    __shared__ float sKs[NG][RH][NMEM];
    __shared__ float swu[NG][NMEM];
    __shared__ float swlu[NG][NMEM];
    __shared__ float sk[NG][RH][DMEM];
    __shared__ float sr[NG][RD];
    __shared__ float snk[NG][RH];
    __shared__ float ssig[NG][RH];
    __shared__ float snM[NG][NMEM];
    __shared__ int   sidx[NG];

    const int tid = threadIdx.x;
    const int b0  = blockIdx.x * NG;
    const int w   = tid >> 6, l = tid & 63;

    // ---- init carries ----
    for (int e = tid; e < NG * NMEM * DPAD; e += 512) ((float*)sM)[e] = 0.f;
    for (int e = tid; e < NG * HDIM; e += 512) ((float*)sh)[e] = 0.f;
    for (int e = tid; e < NG * RH * NMEM; e += 512) ((float*)swr)[e] = 0.f;
    for (int e = tid; e < NG * NMEM; e += 512) { ((float*)swu)[e] = 0.f; ((float*)swlu)[e] = 1.f; }

    float c_reg = 0.f;
    float gxr0 = 0.f, gxr1 = 0.f, gxr2 = 0.f, gxr3 = 0.f;
    int pg = 0, pj = 0;
    if (tid < NG * HDIM) {
        pg = tid / HDIM; pj = tid - pg * HDIM;
        const float* gxp = gx + (size_t)(b0 + pg) * G4H + pj;
        gxr0 = gxp[0]; gxr1 = gxp[HDIM]; gxr2 = gxp[2 * HDIM]; gxr3 = gxp[3 * HDIM];
    }
    __syncthreads();

    // head for batch-group g, step tt (reads sh, sr; whole wave; no LDS temps)
    auto head_store = [&](int g, int tt) {
        float v[NWAY];
#pragma unroll
        for (int o = 0; o < NWAY; ++o) {
            const float* wrow = Wo + o * (HDIM + RD);
            float acc = 0.f;
            for (int j = l; j < HDIM; j += 64) acc += sh[g][j] * wrow[j];
            for (int d = l; d < RD; d += 64) acc += sr[g][d] * wrow[HDIM + d];
#pragma unroll
            for (int off = 32; off; off >>= 1) acc += __shfl_xor(acc, off);
            v[o] = acc + bo[o];
        }
        if (l == 0) {
            float mx = -1e30f;
#pragma unroll
            for (int o = 0; o < NWAY; ++o) { v[o] = sigmoidf_(v[o]); mx = fmaxf(mx, v[o]); }
            float s = 0.f;
#pragma unroll
            for (int o = 0; o < NWAY; ++o) { v[o] = __expf(v[o] - mx); s += v[o]; }
            float inv = 1.f / s;
            float* op = out + ((size_t)tt * BATCH + (b0 + g)) * NWAY;
#pragma unroll
            for (int o = 0; o < NWAY; ++o) op[o] = v[o] * inv;
        }
    };

    // gates GEMV for output-pair p (2 outputs x 2 batches)
    auto gemv_pair = [&](int p) {
        const uint4* wq = Whh_q4 + p;
        float a00 = 0.f, a01 = 0.f, a10 = 0.f, a11 = 0.f;
#pragma unroll 5
        for (int jq = 0; jq < 50; ++jq) {
            uint4 wv = wq[jq * 400];
            float4 h0 = *(const float4*)&sh[0][jq * 4];
            float4 h1 = *(const float4*)&sh[1][jq * 4];
            float we0 = bflo(wv.x), we1 = bfhi(wv.x);
            float wo0 = bflo(wv.y), wo1 = bfhi(wv.y);
            float we2 = bflo(wv.z), we3 = bfhi(wv.z);
            float wo2 = bflo(wv.w), wo3 = bfhi(wv.w);
            a00 += we0 * h0.x + we1 * h0.y + we2 * h0.z + we3 * h0.w;
            a01 += wo0 * h0.x + wo1 * h0.y + wo2 * h0.z + wo3 * h0.w;
            a10 += we0 * h1.x + we1 * h1.y + we2 * h1.z + we3 * h1.w;
            a11 += wo0 * h1.x + wo1 * h1.y + wo2 * h1.z + wo3 * h1.w;
        }
        sgate[0][2 * p]     = a00;
        sgate[0][2 * p + 1] = a01;
        sgate[1][2 * p]     = a10;
        sgate[1][2 * p + 1] = a11;
    };

    for (int t = 0; t < TSTEPS; ++t) {
        // ---- A: gates GEMV (waves 0-5) | head(t-1) + argmin + kth (waves 6,7) ----
        if (tid < 384) {
            gemv_pair(tid);
            if (tid < 16) gemv_pair(tid + 384);
        } else {
            int g = w - 6;
            if (t > 0) head_store(g, t - 1);
            // argmin(wu) -> sidx (first-index ties)
            {
                float v0 = swu[g][l], v1 = swu[g][l + 64];
                bool p1 = (v1 < v0);
                float mv = p1 ? v1 : v0;
                int   mi = p1 ? l + 64 : l;
#pragma unroll
                for (int off = 32; off; off >>= 1) {
                    float ov = __shfl_xor(mv, off);
                    int   oi = __shfl_xor(mi, off);
                    if (ov < mv || (ov == mv && oi < mi)) { mv = ov; mi = oi; }
                }
                if (l == 0) sidx[g] = mi;
            }
            // kth-smallest + wlu
            {
                float o0 = swu[g][l], o1 = swu[g][l + 64];
                float v0 = o0, v1 = o1, kth = 0.f;
#pragma unroll
                for (int it = 0; it < RH; ++it) {
                    bool p1 = (v1 < v0);
                    float mv = p1 ? v1 : v0;
                    int   mi = p1 ? l + 64 : l;
                    for (int off = 32; off; off >>= 1) {
                        float ov = __shfl_xor(mv, off);
                        int   oi = __shfl_xor(mi, off);
                        if (ov < mv || (ov == mv && oi < mi)) { mv = ov; mi = oi; }
                    }
                    kth = mv;
                    if (mi == l) v0 = __builtin_inff();
                    else if (mi == l + 64) v1 = __builtin_inff();
                }
                swlu[g][l]      = (o0 <= kth) ? 1.f : 0.f;
                swlu[g][l + 64] = (o1 <= kth) ? 1.f : 0.f;
            }
        }
        __syncthreads();

        // ---- B: LSTM cell (400 thr); c in regs; prefetch next gx ----
        if (tid < NG * HDIM) {
            float ig = sigmoidf_(sgate[pg][pj] + gxr0);
            float fg = sigmoidf_(sgate[pg][pj + HDIM] + gxr1);
            float gv = ftanh(sgate[pg][pj + 2 * HDIM] + gxr2);
            float og = sigmoidf_(sgate[pg][pj + 3 * HDIM] + gxr3);
            c_reg = fg * c_reg + ig * gv;
            sh[pg][pj] = og * ftanh(c_reg);
            if (t + 1 < TSTEPS) {
                const float* gxp = gx + ((size_t)(t + 1) * BATCH + b0 + pg) * G4H + pj;
                gxr0 = gxp[0]; gxr1 = gxp[HDIM]; gxr2 = gxp[2 * HDIM]; gxr3 = gxp[3 * HDIM];
            }
        }
        __syncthreads();

        // ---- C: key partials (320) | sigma partials (32) ----
        if (tid < 320) {
            int col = tid % RD, c = tid / RD;   // 2 K-chunks of 100 (25 quads)
            const uint2* wq = Wk_q2 + (size_t)(c * 25) * RD + col;
            const int jb = c * 100;
            float a0 = 0.f, a1 = 0.f;
#pragma unroll 5
            for (int q = 0; q < 25; ++q) {
                uint2 wv = wq[q * RD];
                float4 h0 = *(const float4*)&sh[0][jb + q * 4];
                float4 h1 = *(const float4*)&sh[1][jb + q * 4];
                float w0 = bflo(wv.x), w1 = bfhi(wv.x);
                float w2 = bflo(wv.y), w3 = bfhi(wv.y);
                a0 += w0 * h0.x + w1 * h0.y + w2 * h0.z + w3 * h0.w;
                a1 += w0 * h1.x + w1 * h1.y + w2 * h1.z + w3 * h1.w;
            }
            spartK[0][c][col] = a0;
            spartK[1][c][col] = a1;
        } else if (tid < 352) {
            int v = tid - 320; int g = v >> 4, rc = v & 15, r = rc >> 2, cc = rc & 3;
            const float* wrow = Wsm + r * HDIM;
            float a = 0.f;
            for (int j = 50 * cc; j < 50 * cc + 50; ++j) a += sh[g][j] * wrow[j];
            spartS[g][r][cc] = a;
        }
        __syncthreads();

        // ---- D: finalize k (320) | finalize sigma (8) ----
        if (tid < 320) {
            int g = tid / RD, col = tid % RD;
            float s = spartK[g][0][col] + spartK[g][1][col] + bk[col];
            sk[g][col / DMEM][col % DMEM] = ftanh(s);
        } else if (tid < 328) {
            int v = tid - 320; int g = v >> 2, r = v & 3;
            float s = spartS[g][r][0] + spartS[g][r][1]
                    + spartS[g][r][2] + spartS[g][r][3] + bs[r];
            ssig[g][r] = sigmoidf_(ftanh(s));
        }
        __syncthreads();

        // ---- E2'+NF fused: ww, zero-LU-row, M update, cosine dots, norms ----
        if (tid < 256) {
            int g = tid >> 7, m = tid & 127;
            float sg0 = ssig[g][0], sg1 = ssig[g][1], sg2 = ssig[g][2], sg3 = ssig[g][3];
            float wl = swlu[g][m];
            float w0 = sg0 * swr[g][0][m] + (1.f - sg0) * wl;
            float w1 = sg1 * swr[g][1][m] + (1.f - sg1) * wl;
            float w2 = sg2 * swr[g][2][m] + (1.f - sg2) * wl;
            float w3 = sg3 * swr[g][3][m] + (1.f - sg3) * wl;
            sww[g][0][m] = w0; sww[g][1][m] = w1;
            sww[g][2][m] = w2; sww[g][3][m] = w3;
            bool zr = (m == sidx[g]);
            float d0 = 0.f, d1 = 0.f, d2 = 0.f, d3 = 0.f, nn = 0.f;
#pragma unroll
            for (int q = 0; q < 10; ++q) {
                int d = q * 4;
                float4 mv = *(const float4*)&sM[g][m][d];
                float4 k0 = *(const float4*)&sk[g][0][d];
                float4 k1 = *(const float4*)&sk[g][1][d];
                float4 k2 = *(const float4*)&sk[g][2][d];
                float4 k3 = *(const float4*)&sk[g][3][d];
                float4 o;
                o.x = (zr ? 0.f : mv.x) + w0 * k0.x + w1 * k1.x + w2 * k2.x + w3 * k3.x;
                o.y = (zr ? 0.f : mv.y) + w0 * k0.y + w1 * k1.y + w2 * k2.y + w3 * k3.y;
                o.z = (zr ? 0.f : mv.z) + w0 * k0.z + w1 * k1.z + w2 * k2.z + w3 * k3.z;
                o.w = (zr ? 0.f : mv.w) + w0 * k0.w + w1 * k1.w + w2 * k2.w + w3 * k3.w;
                *(float4*)&sM[g][m][d] = o;
                d0 += k0.x * o.x + k0.y * o.y + k0.z * o.z + k0.w * o.w;
                d1 += k1.x * o.x + k1.y * o.y + k1.z * o.z + k1.w * o.w;
                d2 += k2.x * o.x + k2.y * o.y + k2.z * o.z + k2.w * o.w;
                d3 += k3.x * o.x + k3.y * o.y + k3.z * o.z + k3.w * o.w;
                nn += o.x * o.x + o.y * o.y + o.z * o.z + o.w * o.w;
            }
            sKs[g][0][m] = d0; sKs[g][1][m] = d1;
            sKs[g][2][m] = d2; sKs[g][3][m] = d3;
            snM[g][m] = sqrtf(nn);
        } else if (tid < 264) {
            int v = tid - 256; int g2 = v >> 2, r2 = v & 3;
            float a0 = 0.f, a1 = 0.f, a2 = 0.f, a3 = 0.f;
#pragma unroll
            for (int q = 0; q < 10; ++q) {
                float4 kv = *(const float4*)&sk[g2][r2][q * 4];
                a0 += kv.x * kv.x; a1 += kv.y * kv.y;
                a2 += kv.z * kv.z; a3 += kv.w * kv.w;
            }
            snk[g2][r2] = sqrtf((a0 + a1) + (a2 + a3));
        }
        __syncthreads();

        // ---- G: cosine normalize + softmax over m -> wr_new (8 waves) ----
        {
            int g = w >> 2, r = w & 3, ln = l;
            float ink = snk[g][r];
            float a = sKs[g][r][ln] / (ink * snM[g][ln]);
            float b = sKs[g][r][ln + 64] / (ink * snM[g][ln + 64]);
            float mx = fmaxf(a, b);
#pragma unroll
            for (int off = 32; off; off >>= 1) mx = fmaxf(mx, __shfl_xor(mx, off));
            float ea = __expf(a - mx), eb = __expf(b - mx);
            float s = ea + eb;
#pragma unroll
            for (int off = 32; off; off >>= 1) s += __shfl_xor(s, off);
            float inv = 1.f / s;
            swr[g][r][ln]      = ea * inv;
            swr[g][r][ln + 64] = eb * inv;
        }
        __syncthreads();

        // ---- H: read vectors (80, float4) | usage update (256) ----
        if (tid < 80) {
            int g = tid / 40, rd4 = tid % 40, r = rd4 / 10, d4 = rd4 % 10;
            float a0 = 0.f, a1 = 0.f, a2 = 0.f, a3 = 0.f;
            for (int m = 0; m < NMEM; ++m) {
                float wv = swr[g][r][m];
                float4 mv = *(const float4*)&sM[g][m][d4 * 4];
                a0 += wv * mv.x; a1 += wv * mv.y;
                a2 += wv * mv.z; a3 += wv * mv.w;
            }
            float4 res = {a0, a1, a2, a3};
            *(float4*)&sr[g][r * DMEM + d4 * 4] = res;
        } else if (tid >= 256) {
            int e = tid - 256;
            int g = e >> 7, m = e & 127;
            float wu = GAMMA_ * swu[g][m];
#pragma unroll
            for (int r = 0; r < RH; ++r) wu += swr[g][r][m] + sww[g][r][m];
            swu[g][m] = wu;
        }
        __syncthreads();
    }

    // ---- epilogue: head for the final step ----
    if (w >= 6) head_store(w - 6, TSTEPS - 1);
}

extern "C" void kernel_launch(void* const* d_in, const int* in_sizes, int n_in,
                              void* d_out, int out_size, void* d_ws, size_t ws_size,
                              hipStream_t stream) {
    const float* x    = (const float*)d_in[0];
    const float* W_ih = (const float*)d_in[1];
    const float* W_hh = (const float*)d_in[2];
    const float* b_ih = (const float*)d_in[3];
    const float* b_hh = (const float*)d_in[4];
    const float* Wk   = (const float*)d_in[5];
    const float* bk   = (const float*)d_in[6];
    const float* Wsm  = (const float*)d_in[7];
    const float* bs   = (const float*)d_in[8];
    const float* Wo   = (const float*)d_in[9];
    const float* bo   = (const float*)d_in[10];
    float* out = (float*)d_out;

    const size_t gx_elems  = (size_t)TSTEPS * BATCH * G4H;  // 40,960,000 f32
    const size_t whh_q4_e  = (size_t)50 * 400;              // uint4 (16B)
    const size_t wk_q2_e   = (size_t)50 * 160;              // uint2 (8B)
    const size_t a_elems   = (size_t)TSTEPS * BATCH * KP;   // u16 each
    const size_t w_elems   = (size_t)2 * WROWS * KP;        // u16
    const size_t need_base = gx_elems * 4 + whh_q4_e * 16 + wk_q2_e * 8;
    const size_t need_mfma = need_base + (2 * a_elems + w_elems) * 2;
    if (ws_size < need_base) return;

    float* gxb = (float*)d_ws;
    uint4* Whh_q4 = (uint4*)(gxb + gx_elems);
    uint2* Wk_q2  = (uint2*)(Whh_q4 + whh_q4_e);

    {
        int tot = (int)(whh_q4_e + wk_q2_e);
        convert_recQ<<<dim3((tot + 255) / 256), dim3(256), 0, stream>>>(W_hh, Wk, Whh_q4, Wk_q2);
    }

    if (ws_size >= need_mfma) {
        unsigned short* Ahi = (unsigned short*)(Wk_q2 + wk_q2_e);
        unsigned short* Alo = Ahi + a_elems;
        unsigned short* Wpk = Alo + a_elems;
        convert_A<<<dim3(2, TSTEPS * BATCH), dim3(256), 0, stream>>>(x, Ahi, Alo);
        convert_W<<<dim3(2, WROWS, 2), dim3(256), 0, stream>>>(W_ih, Wpk);
        gx_gemm_mfma<<<dim3(7, (TSTEPS * BATCH) / 128), dim3(256), 0, stream>>>(
            Ahi, Alo, Wpk, b_ih, b_hh, gxb);
    } else {
        gx_gemm<<<dim3(G4H / 80, (TSTEPS * BATCH) / 128), dim3(256), 0, stream>>>(
            x, W_ih, b_ih, b_hh, gxb);
    }

    ntm_scan<<<dim3(BATCH / NG), dim3(512), 0, stream>>>(
        gxb, Whh_q4, Wk_q2, bk, Wsm, bs, Wo, bo, out);
}

// Round 11
// 1746.842 us; speedup vs baseline: 1.0318x; 1.0318x over previous
//
#include <hip/hip_runtime.h>
#include <stdint.h>

#define TSTEPS 50
#define BATCH  1024
#define INDIM  405
#define KP     448      // padded K for gx GEMM (7 x 64)
#define HDIM   200
#define G4H    800      // 4*H
#define NMEM   128
#define DMEM   40
#define DPAD   44       // sM row stride: 16B-aligned
#define RH     4
#define RD     160      // RH*DMEM
#define NWAY   5
#define GAMMA_ 0.99f
#define NG     2        // batches per block; 512 blocks, 512 thr -> 2 blocks/CU
#define WROWS  928      // gx GEMM W rows padded

typedef __attribute__((ext_vector_type(8))) short short8;
typedef __attribute__((ext_vector_type(4))) float f32x4;

__device__ __forceinline__ float sigmoidf_(float x) {
    return 1.f / (1.f + __expf(-x));
}
__device__ __forceinline__ float ftanh(float x) {
    float e = __expf(2.f * x);
    return 1.f - 2.f / (e + 1.f);
}
__device__ __forceinline__ unsigned short f2bf(float f) {   // RNE f32->bf16
    uint32_t u = __float_as_uint(f);
    uint32_t r = u + 0x7FFFu + ((u >> 16) & 1u);
    return (unsigned short)(r >> 16);
}
__device__ __forceinline__ float bf2f(unsigned short h) {
    return __uint_as_float(((uint32_t)h) << 16);
}
__device__ __forceinline__ float bflo(uint32_t u) { return __uint_as_float(u << 16); }
__device__ __forceinline__ float bfhi(uint32_t u) { return __uint_as_float(u & 0xFFFF0000u); }

// ---- quad-pack recurrent weights (round-8 layout) --------------------------
__global__ __launch_bounds__(256) void convert_recQ(const float* __restrict__ W_hh,
                                                    const float* __restrict__ Wk,
                                                    uint4* __restrict__ Whh_q4,
                                                    uint2* __restrict__ Wk_q2) {
    int i = blockIdx.x * 256 + threadIdx.x;
    if (i < 50 * 400) {
        int jq = i / 400, p = i % 400;
        int j = jq * 4;
        const float* r0 = W_hh + (2 * p) * HDIM;
        const float* r1 = W_hh + (2 * p + 1) * HDIM;
        uint4 v;
        v.x = (uint32_t)f2bf(r0[j])     | ((uint32_t)f2bf(r0[j + 1]) << 16);
        v.y = (uint32_t)f2bf(r1[j])     | ((uint32_t)f2bf(r1[j + 1]) << 16);
        v.z = (uint32_t)f2bf(r0[j + 2]) | ((uint32_t)f2bf(r0[j + 3]) << 16);
        v.w = (uint32_t)f2bf(r1[j + 2]) | ((uint32_t)f2bf(r1[j + 3]) << 16);
        Whh_q4[i] = v;
    } else if (i < 50 * 400 + 50 * 160) {
        int e = i - 50 * 400;
        int jq = e / 160, col = e % 160;
        int j = jq * 4;
        const float* r = Wk + col * HDIM;
        uint2 v;
        v.x = (uint32_t)f2bf(r[j])     | ((uint32_t)f2bf(r[j + 1]) << 16);
        v.y = (uint32_t)f2bf(r[j + 2]) | ((uint32_t)f2bf(r[j + 3]) << 16);
        Wk_q2[e] = v;
    }
}

// ---------------- split f32 -> (hi, lo) bf16, zero-padded K (gx GEMM) ------
__global__ __launch_bounds__(256) void convert_A(const float* __restrict__ x,
                                                 unsigned short* __restrict__ Ahi,
                                                 unsigned short* __restrict__ Alo) {
    int c = blockIdx.x * 256 + threadIdx.x;
    int r = blockIdx.y;
    if (c >= KP) return;
    float v = (c < INDIM) ? x[(size_t)r * INDIM + c] : 0.f;
    unsigned short hi = f2bf(v);
    unsigned short lo = f2bf(v - bf2f(hi));
    size_t o = (size_t)r * KP + c;
    Ahi[o] = hi;
    Alo[o] = lo;
}

__global__ __launch_bounds__(256) void convert_W(const float* __restrict__ W_ih,
                                                 unsigned short* __restrict__ Wpk) {
    int c = blockIdx.x * 256 + threadIdx.x;
    int n = blockIdx.y;
    int sec = blockIdx.z;
    if (c >= KP) return;
    float v = (n < G4H && c < INDIM) ? W_ih[(size_t)n * INDIM + c] : 0.f;
    unsigned short hi = f2bf(v);
    size_t o = (size_t)sec * WROWS * KP + (size_t)n * KP + c;
    Wpk[o] = (sec == 0) ? hi : f2bf(v - bf2f(hi));
}

// ---------------- gx GEMM via 3-term split-bf16 MFMA ----------------------
__global__ __launch_bounds__(256) void gx_gemm_mfma(
        const unsigned short* __restrict__ Ahi,
        const unsigned short* __restrict__ Alo,
        const unsigned short* __restrict__ Wpk,
        const float* __restrict__ b_ih, const float* __restrict__ b_hh,
        float* __restrict__ gx) {
    __shared__ unsigned short Alds[128 * 64];
    __shared__ unsigned short Blds[128 * 64];
    const int tid = threadIdx.x;
    const int wv = tid >> 6, ln = tid & 63;
    const int wr = wv >> 1, wc = wv & 1;
    const int n0 = blockIdx.x * 128;
    const int m0 = blockIdx.y * 128;

    f32x4 acc[4][4];
#pragma unroll
    for (int m = 0; m < 4; ++m)
#pragma unroll
        for (int n = 0; n < 4; ++n) acc[m][n] = (f32x4){0.f, 0.f, 0.f, 0.f};

    int erow[4], ecol[4];
#pragma unroll
    for (int i = 0; i < 4; ++i) {
        int e = (i * 4 + wv) * 512 + ln * 8;
        erow[i] = e >> 6;
        ecol[i] = e & 63;
    }

    const unsigned short* Whi = Wpk;
    const unsigned short* Wlo = Wpk + (size_t)WROWS * KP;

#pragma unroll 1
    for (int s = 0; s < 3; ++s) {
        const unsigned short* Ab = ((s == 2) ? Alo : Ahi) + (size_t)m0 * KP;
        const unsigned short* Bb = ((s == 1) ? Wlo : Whi) + (size_t)n0 * KP;

        short8 ar[4], br[4];
#pragma unroll
        for (int i = 0; i < 4; ++i) {
            ar[i] = *(const short8*)&Ab[(size_t)erow[i] * KP + ecol[i]];
            br[i] = *(const short8*)&Bb[(size_t)erow[i] * KP + ecol[i]];
        }

#pragma unroll 1
        for (int k0 = 0; k0 < KP; k0 += 64) {
            __syncthreads();
#pragma unroll
            for (int i = 0; i < 4; ++i) {
                int e = (i * 4 + wv) * 512 + ln * 8;
                *(short8*)&Alds[e] = ar[i];
                *(short8*)&Blds[e] = br[i];
            }
            __syncthreads();
            if (k0 + 64 < KP) {
#pragma unroll
                for (int i = 0; i < 4; ++i) {
                    ar[i] = *(const short8*)&Ab[(size_t)erow[i] * KP + k0 + 64 + ecol[i]];
                    br[i] = *(const short8*)&Bb[(size_t)erow[i] * KP + k0 + 64 + ecol[i]];
                }
            }
#pragma unroll
            for (int ks = 0; ks < 2; ++ks) {
                short8 af[4], bf[4];
                int kcol = ks * 32 + (ln >> 4) * 8;
#pragma unroll
                for (int m = 0; m < 4; ++m) {
                    int row = wr * 64 + m * 16 + (ln & 15);
                    af[m] = *(const short8*)&Alds[row * 64 + kcol];
                }
#pragma unroll
                for (int n = 0; n < 4; ++n) {
                    int row = wc * 64 + n * 16 + (ln & 15);
                    bf[n] = *(const short8*)&Blds[row * 64 + kcol];
                }
#pragma unroll
                for (int m = 0; m < 4; ++m)
#pragma unroll
                    for (int n = 0; n < 4; ++n)
                        acc[m][n] = __builtin_amdgcn_mfma_f32_16x16x32_bf16(
                            af[m], bf[n], acc[m][n], 0, 0, 0);
            }
        }
    }

#pragma unroll
    for (int n = 0; n < 4; ++n) {
        int col = n0 + wc * 64 + n * 16 + (ln & 15);
        if (col >= G4H) continue;
        float bias = b_ih[col] + b_hh[col];
#pragma unroll
        for (int m = 0; m < 4; ++m) {
#pragma unroll
            for (int j = 0; j < 4; ++j) {
                int row = m0 + wr * 64 + m * 16 + (ln >> 4) * 4 + j;
                gx[(size_t)row * G4H + col] = acc[m][n][j] + bias;
            }
        }
    }
}

// ---------------- f32 fallback GEMM ---------------------------------------
__global__ __launch_bounds__(256) void gx_gemm(const float* __restrict__ x,
                                               const float* __restrict__ W_ih,
                                               const float* __restrict__ b_ih,
                                               const float* __restrict__ b_hh,
                                               float* __restrict__ gx) {
    const int BM = 128, BN = 80, BK = 16;
    __shared__ float As[BK][BM];
    __shared__ float Bs[BK][BN];
    int m0 = blockIdx.y * BM;
    int n0 = blockIdx.x * BN;
    int tid = threadIdx.x;
    int tm = tid >> 4, tn = tid & 15;
    float acc[8][5];
#pragma unroll
    for (int i = 0; i < 8; ++i)
#pragma unroll
        for (int j = 0; j < 5; ++j) acc[i][j] = 0.f;

    for (int k0 = 0; k0 < INDIM; k0 += BK) {
        {
            int row = tid >> 1, kk = (tid & 1) * 8;
            const float* ap = x + (size_t)(m0 + row) * INDIM + k0 + kk;
#pragma unroll
            for (int i = 0; i < 8; ++i)
                As[kk + i][row] = (k0 + kk + i < INDIM) ? ap[i] : 0.f;
        }
        if (tid < 160) {
            int col = tid >> 1, kk = (tid & 1) * 8;
            const float* bp = W_ih + (size_t)(n0 + col) * INDIM + k0 + kk;
#pragma unroll
            for (int i = 0; i < 8; ++i)
                Bs[kk + i][col] = (k0 + kk + i < INDIM) ? bp[i] : 0.f;
        }
        __syncthreads();
#pragma unroll
        for (int k = 0; k < BK; ++k) {
            float a[8], b[5];
#pragma unroll
            for (int i = 0; i < 8; ++i) a[i] = As[k][tm * 8 + i];
#pragma unroll
            for (int j = 0; j < 5; ++j) b[j] = Bs[k][tn * 5 + j];
#pragma unroll
            for (int i = 0; i < 8; ++i)
#pragma unroll
                for (int j = 0; j < 5; ++j) acc[i][j] += a[i] * b[j];
        }
        __syncthreads();
    }
#pragma unroll
    for (int j = 0; j < 5; ++j) {
        int n = n0 + tn * 5 + j;
        float bias = b_ih[n] + b_hh[n];
#pragma unroll
        for (int i = 0; i < 8; ++i) {
            int m = m0 + tm * 8 + i;
            gx[(size_t)m * G4H + n] = acc[i][j] + bias;
        }
    }
}

// ---------------- persistent NTM scan: NG=2, 512 thr, 7 barriers/step ------
__global__ __launch_bounds__(512, 4) void ntm_scan(
        const float* __restrict__ gx,          // [T][B][800]
        const uint4* __restrict__ Whh_q4,      // [50][400] quad-packed bf16
        const uint2* __restrict__ Wk_q2,       // [50][160] quad-packed bf16
        const float* __restrict__ bk,
        const float* __restrict__ Wsm,         // [4][200]
        const float* __restrict__ bs,
        const float* __restrict__ Wo,          // [5][360]
        const float* __restrict__ bo,
        float* __restrict__ out) {             // [T][B][5]
    __shared__ float sM[NG][NMEM][DPAD];
    __shared__ float sh[NG][HDIM];
    __shared__ float sgate[NG][G4H];
    __shared__ float spartK[NG][2][RD];
    __shared__ float spartS[NG][RH][4];
    __shared__ float swr[NG][RH][NMEM];
    __shared__ float sww[NG][RH][NMEM];
    __shared__ float sKs[NG][RH][NMEM];
    __shared__ float swu[NG][NMEM];
    __shared__ float swlu[NG][NMEM];
    __shared__ float sk[NG][RH][DMEM];
    __shared__ float sr[NG][RD];
    __shared__ float snk[NG][RH];
    __shared__ float ssig[NG][RH];
    __shared__ float snM[NG][NMEM];
    __shared__ int   sidx[NG];

    const int tid = threadIdx.x;
    const int b0  = blockIdx.x * NG;
    const int w   = tid >> 6, l = tid & 63;

    // ---- init carries ----
    for (int e = tid; e < NG * NMEM * DPAD; e += 512) ((float*)sM)[e] = 0.f;
    for (int e = tid; e < NG * HDIM; e += 512) ((float*)sh)[e] = 0.f;
    for (int e = tid; e < NG * RH * NMEM; e += 512) ((float*)swr)[e] = 0.f;
    for (int e = tid; e < NG * NMEM; e += 512) { ((float*)swu)[e] = 0.f; ((float*)swlu)[e] = 1.f; }

    float c_reg = 0.f;
    float gxr0 = 0.f, gxr1 = 0.f, gxr2 = 0.f, gxr3 = 0.f;
    int pg = 0, pj = 0;
    if (tid < NG * HDIM) {
        pg = tid / HDIM; pj = tid - pg * HDIM;
        const float* gxp = gx + (size_t)(b0 + pg) * G4H + pj;
        gxr0 = gxp[0]; gxr1 = gxp[HDIM]; gxr2 = gxp[2 * HDIM]; gxr3 = gxp[3 * HDIM];
    }
    __syncthreads();

    // head for batch-group g, step tt (reads sh, sr; whole wave; lane l)
    auto head_store = [&](int g, int tt) {
        float v[NWAY];
#pragma unroll
        for (int o = 0; o < NWAY; ++o) {
            const float* wrow = Wo + o * (HDIM + RD);
            float acc = 0.f;
            for (int j = l; j < HDIM; j += 64) acc += sh[g][j] * wrow[j];
            for (int d = l; d < RD; d += 64) acc += sr[g][d] * wrow[HDIM + d];
#pragma unroll
            for (int off = 32; off; off >>= 1) acc += __shfl_xor(acc, off);
            v[o] = acc + bo[o];
        }
        if (l == 0) {
            float mx = -1e30f;
#pragma unroll
            for (int o = 0; o < NWAY; ++o) { v[o] = sigmoidf_(v[o]); mx = fmaxf(mx, v[o]); }
            float s = 0.f;
#pragma unroll
            for (int o = 0; o < NWAY; ++o) { v[o] = __expf(v[o] - mx); s += v[o]; }
            float inv = 1.f / s;
            float* op = out + ((size_t)tt * BATCH + (b0 + g)) * NWAY;
#pragma unroll
            for (int o = 0; o < NWAY; ++o) op[o] = v[o] * inv;
        }
    };

    for (int t = 0; t < TSTEPS; ++t) {
        // ---- A: gates GEMV (thr 0-399, ONE pair each) | wave 7: head(t-1)+argmin+kth ----
        if (tid < 400) {
            const uint4* wq = Whh_q4 + tid;
            float a00 = 0.f, a01 = 0.f, a10 = 0.f, a11 = 0.f;
#pragma unroll 5
            for (int jq = 0; jq < 50; ++jq) {
                uint4 wv = wq[jq * 400];
                float4 h0 = *(const float4*)&sh[0][jq * 4];
                float4 h1 = *(const float4*)&sh[1][jq * 4];
                float we0 = bflo(wv.x), we1 = bfhi(wv.x);
                float wo0 = bflo(wv.y), wo1 = bfhi(wv.y);
                float we2 = bflo(wv.z), we3 = bfhi(wv.z);
                float wo2 = bflo(wv.w), wo3 = bfhi(wv.w);
                a00 += we0 * h0.x + we1 * h0.y + we2 * h0.z + we3 * h0.w;
                a01 += wo0 * h0.x + wo1 * h0.y + wo2 * h0.z + wo3 * h0.w;
                a10 += we0 * h1.x + we1 * h1.y + we2 * h1.z + we3 * h1.w;
                a11 += wo0 * h1.x + wo1 * h1.y + wo2 * h1.z + wo3 * h1.w;
            }
            sgate[0][2 * tid]     = a00;
            sgate[0][2 * tid + 1] = a01;
            sgate[1][2 * tid]     = a10;
            sgate[1][2 * tid + 1] = a11;
        } else if (w == 7) {
            if (t > 0) { head_store(0, t - 1); head_store(1, t - 1); }
#pragma unroll
            for (int g = 0; g < NG; ++g) {
                // argmin(wu) -> sidx (first-index ties)
                {
                    float v0 = swu[g][l], v1 = swu[g][l + 64];
                    bool p1 = (v1 < v0);
                    float mv = p1 ? v1 : v0;
                    int   mi = p1 ? l + 64 : l;
#pragma unroll
                    for (int off = 32; off; off >>= 1) {
                        float ov = __shfl_xor(mv, off);
                        int   oi = __shfl_xor(mi, off);
                        if (ov < mv || (ov == mv && oi < mi)) { mv = ov; mi = oi; }
                    }
                    if (l == 0) sidx[g] = mi;
                }
                // kth-smallest + wlu
                {
                    float o0 = swu[g][l], o1 = swu[g][l + 64];
                    float v0 = o0, v1 = o1, kth = 0.f;
#pragma unroll
                    for (int it = 0; it < RH; ++it) {
                        bool p1 = (v1 < v0);
                        float mv = p1 ? v1 : v0;
                        int   mi = p1 ? l + 64 : l;
                        for (int off = 32; off; off >>= 1) {
                            float ov = __shfl_xor(mv, off);
                            int   oi = __shfl_xor(mi, off);
                            if (ov < mv || (ov == mv && oi < mi)) { mv = ov; mi = oi; }
                        }
                        kth = mv;
                        if (mi == l) v0 = __builtin_inff();
                        else if (mi == l + 64) v1 = __builtin_inff();
                    }
                    swlu[g][l]      = (o0 <= kth) ? 1.f : 0.f;
                    swlu[g][l + 64] = (o1 <= kth) ? 1.f : 0.f;
                }
            }
        }
        __syncthreads();

        // ---- B: LSTM cell (400 thr); c in regs; prefetch next gx ----
        if (tid < NG * HDIM) {
            float ig = sigmoidf_(sgate[pg][pj] + gxr0);
            float fg = sigmoidf_(sgate[pg][pj + HDIM] + gxr1);
            float gv = ftanh(sgate[pg][pj + 2 * HDIM] + gxr2);
            float og = sigmoidf_(sgate[pg][pj + 3 * HDIM] + gxr3);
            c_reg = fg * c_reg + ig * gv;
            sh[pg][pj] = og * ftanh(c_reg);
            if (t + 1 < TSTEPS) {
                const float* gxp = gx + ((size_t)(t + 1) * BATCH + b0 + pg) * G4H + pj;
                gxr0 = gxp[0]; gxr1 = gxp[HDIM]; gxr2 = gxp[2 * HDIM]; gxr3 = gxp[3 * HDIM];
            }
        }
        __syncthreads();

        // ---- C: key partials (320) | sigma partials (32) ----
        if (tid < 320) {
            int col = tid % RD, c = tid / RD;   // 2 K-chunks of 100 (25 quads)
            const uint2* wq = Wk_q2 + (size_t)(c * 25) * RD + col;
            const int jb = c * 100;
            float a0 = 0.f, a1 = 0.f;
#pragma unroll 5
            for (int q = 0; q < 25; ++q) {
                uint2 wv = wq[q * RD];
                float4 h0 = *(const float4*)&sh[0][jb + q * 4];
                float4 h1 = *(const float4*)&sh[1][jb + q * 4];
                float w0 = bflo(wv.x), w1 = bfhi(wv.x);
                float w2 = bflo(wv.y), w3 = bfhi(wv.y);
                a0 += w0 * h0.x + w1 * h0.y + w2 * h0.z + w3 * h0.w;
                a1 += w0 * h1.x + w1 * h1.y + w2 * h1.z + w3 * h1.w;
            }
            spartK[0][c][col] = a0;
            spartK[1][c][col] = a1;
        } else if (tid < 352) {
            int v = tid - 320; int g = v >> 4, rc = v & 15, r = rc >> 2, cc = rc & 3;
            const float* wrow = Wsm + r * HDIM;
            float a = 0.f;
            for (int j = 50 * cc; j < 50 * cc + 50; ++j) a += sh[g][j] * wrow[j];
            spartS[g][r][cc] = a;
        }
        __syncthreads();

        // ---- D: finalize k (320) | finalize sigma (8) ----
        if (tid < 320) {
            int g = tid / RD, col = tid % RD;
            float s = spartK[g][0][col] + spartK[g][1][col] + bk[col];
            sk[g][col / DMEM][col % DMEM] = ftanh(s);
        } else if (tid < 328) {
            int v = tid - 320; int g = v >> 2, r = v & 3;
            float s = spartS[g][r][0] + spartS[g][r][1]
                    + spartS[g][r][2] + spartS[g][r][3] + bs[r];
            ssig[g][r] = sigmoidf_(ftanh(s));
        }
        __syncthreads();

        // ---- E2'+NF fused: ww, zero-LU-row, M update, cosine dots, norms ----
        if (tid < 256) {
            int g = tid >> 7, m = tid & 127;
            float sg0 = ssig[g][0], sg1 = ssig[g][1], sg2 = ssig[g][2], sg3 = ssig[g][3];
            float wl = swlu[g][m];
            float w0 = sg0 * swr[g][0][m] + (1.f - sg0) * wl;
            float w1 = sg1 * swr[g][1][m] + (1.f - sg1) * wl;
            float w2 = sg2 * swr[g][2][m] + (1.f - sg2) * wl;
            float w3 = sg3 * swr[g][3][m] + (1.f - sg3) * wl;
            sww[g][0][m] = w0; sww[g][1][m] = w1;
            sww[g][2][m] = w2; sww[g][3][m] = w3;
            bool zr = (m == sidx[g]);
            float d0 = 0.f, d1 = 0.f, d2 = 0.f, d3 = 0.f, nn = 0.f;
#pragma unroll
            for (int q = 0; q < 10; ++q) {
                int d = q * 4;
                float4 mv = *(const float4*)&sM[g][m][d];
                float4 k0 = *(const float4*)&sk[g][0][d];
                float4 k1 = *(const float4*)&sk[g][1][d];
                float4 k2 = *(const float4*)&sk[g][2][d];
                float4 k3 = *(const float4*)&sk[g][3][d];
                float4 o;
                o.x = (zr ? 0.f : mv.x) + w0 * k0.x + w1 * k1.x + w2 * k2.x + w3 * k3.x;
                o.y = (zr ? 0.f : mv.y) + w0 * k0.y + w1 * k1.y + w2 * k2.y + w3 * k3.y;
                o.z = (zr ? 0.f : mv.z) + w0 * k0.z + w1 * k1.z + w2 * k2.z + w3 * k3.z;
                o.w = (zr ? 0.f : mv.w) + w0 * k0.w + w1 * k1.w + w2 * k2.w + w3 * k3.w;
                *(float4*)&sM[g][m][d] = o;
                d0 += k0.x * o.x + k0.y * o.y + k0.z * o.z + k0.w * o.w;
                d1 += k1.x * o.x + k1.y * o.y + k1.z * o.z + k1.w * o.w;
                d2 += k2.x * o.x + k2.y * o.y + k2.z * o.z + k2.w * o.w;
                d3 += k3.x * o.x + k3.y * o.y + k3.z * o.z + k3.w * o.w;
                nn += o.x * o.x + o.y * o.y + o.z * o.z + o.w * o.w;
            }
            sKs[g][0][m] = d0; sKs[g][1][m] = d1;
            sKs[g][2][m] = d2; sKs[g][3][m] = d3;
            snM[g][m] = sqrtf(nn);
        } else if (tid < 264) {
            int v = tid - 256; int g2 = v >> 2, r2 = v & 3;
            float a0 = 0.f, a1 = 0.f, a2 = 0.f, a3 = 0.f;
#pragma unroll
            for (int q = 0; q < 10; ++q) {
                float4 kv = *(const float4*)&sk[g2][r2][q * 4];
                a0 += kv.x * kv.x; a1 += kv.y * kv.y;
                a2 += kv.z * kv.z; a3 += kv.w * kv.w;
            }
            snk[g2][r2] = sqrtf((a0 + a1) + (a2 + a3));
        }
        __syncthreads();

        // ---- G: cosine normalize + softmax over m -> wr_new (8 waves) ----
        {
            int g = w >> 2, r = w & 3, ln = l;
            float ink = snk[g][r];
            float a = sKs[g][r][ln] / (ink * snM[g][ln]);
            float b = sKs[g][r][ln + 64] / (ink * snM[g][ln + 64]);
            float mx = fmaxf(a, b);
#pragma unroll
            for (int off = 32; off; off >>= 1) mx = fmaxf(mx, __shfl_xor(mx, off));
            float ea = __expf(a - mx), eb = __expf(b - mx);
            float s = ea + eb;
#pragma unroll
            for (int off = 32; off; off >>= 1) s += __shfl_xor(s, off);
            float inv = 1.f / s;
            swr[g][r][ln]      = ea * inv;
            swr[g][r][ln + 64] = eb * inv;
        }
        __syncthreads();

        // ---- H: read vectors (80, float4) | usage update (256) ----
        if (tid < 80) {
            int g = tid / 40, rd4 = tid % 40, r = rd4 / 10, d4 = rd4 % 10;
            float a0 = 0.f, a1 = 0.f, a2 = 0.f, a3 = 0.f;
            for (int m = 0; m < NMEM; ++m) {
                float wv = swr[g][r][m];
                float4 mv = *(const float4*)&sM[g][m][d4 * 4];
                a0 += wv * mv.x; a1 += wv * mv.y;
                a2 += wv * mv.z; a3 += wv * mv.w;
            }
            float4 res = {a0, a1, a2, a3};
            *(float4*)&sr[g][r * DMEM + d4 * 4] = res;
        } else if (tid >= 256) {
            int e = tid - 256;
            int g = e >> 7, m = e & 127;
            float wu = GAMMA_ * swu[g][m];
#pragma unroll
            for (int r = 0; r < RH; ++r) wu += swr[g][r][m] + sww[g][r][m];
            swu[g][m] = wu;
        }
        __syncthreads();
    }

    // ---- epilogue: head for the final step ----
    if (w == 7) { head_store(0, TSTEPS - 1); head_store(1, TSTEPS - 1); }
}

extern "C" void kernel_launch(void* const* d_in, const int* in_sizes, int n_in,
                              void* d_out, int out_size, void* d_ws, size_t ws_size,
                              hipStream_t stream) {
    const float* x    = (const float*)d_in[0];
    const float* W_ih = (const float*)d_in[1];
    const float* W_hh = (const float*)d_in[2];
    const float* b_ih = (const float*)d_in[3];
    const float* b_hh = (const float*)d_in[4];
    const float* Wk   = (const float*)d_in[5];
    const float* bk   = (const float*)d_in[6];
    const float* Wsm  = (const float*)d_in[7];
    const float* bs   = (const float*)d_in[8];
    const float* Wo   = (const float*)d_in[9];
    const float* bo   = (const float*)d_in[10];
    float* out = (float*)d_out;

    const size_t gx_elems  = (size_t)TSTEPS * BATCH * G4H;  // 40,960,000 f32
    const size_t whh_q4_e  = (size_t)50 * 400;              // uint4 (16B)
    const size_t wk_q2_e   = (size_t)50 * 160;              // uint2 (8B)
    const size_t a_elems   = (size_t)TSTEPS * BATCH * KP;   // u16 each
    const size_t w_elems   = (size_t)2 * WROWS * KP;        // u16
    const size_t need_base = gx_elems * 4 + whh_q4_e * 16 + wk_q2_e * 8;
    const size_t need_mfma = need_base + (2 * a_elems + w_elems) * 2;
    if (ws_size < need_base) return;

    float* gxb = (float*)d_ws;
    uint4* Whh_q4 = (uint4*)(gxb + gx_elems);
    uint2* Wk_q2  = (uint2*)(Whh_q4 + whh_q4_e);

    {
        int tot = (int)(whh_q4_e + wk_q2_e);
        convert_recQ<<<dim3((tot + 255) / 256), dim3(256), 0, stream>>>(W_hh, Wk, Whh_q4, Wk_q2);
    }

    if (ws_size >= need_mfma) {
        unsigned short* Ahi = (unsigned short*)(Wk_q2 + wk_q2_e);
        unsigned short* Alo = Ahi + a_elems;
        unsigned short* Wpk = Alo + a_elems;
        convert_A<<<dim3(2, TSTEPS * BATCH), dim3(256), 0, stream>>>(x, Ahi, Alo);
        convert_W<<<dim3(2, WROWS, 2), dim3(256), 0, stream>>>(W_ih, Wpk);
        gx_gemm_mfma<<<dim3(7, (TSTEPS * BATCH) / 128), dim3(256), 0, stream>>>(
            Ahi, Alo, Wpk, b_ih, b_hh, gxb);
    } else {
        gx_gemm<<<dim3(G4H / 80, (TSTEPS * BATCH) / 128), dim3(256), 0, stream>>>(
            x, W_ih, b_ih, b_hh, gxb);
    }

    ntm_scan<<<dim3(BATCH / NG), dim3(512), 0, stream>>>(
        gxb, Whh_q4, Wk_q2, bk, Wsm, bs, Wo, bo, out);
}

// Round 12
// 1558.690 us; speedup vs baseline: 1.1563x; 1.1207x over previous
//
#include <hip/hip_runtime.h>
#include <stdint.h>

#define TSTEPS 50
#define BATCH  1024
#define INDIM  405
#define KP     448      // padded K for gx GEMM (7 x 64)
#define HDIM   200
#define G4H    800      // 4*H
#define NMEM   128
#define DMEM   40
#define DPAD   44       // sM row stride: 16B-aligned
#define RH     4
#define RD     160      // RH*DMEM
#define NWAY   5
#define GAMMA_ 0.99f
#define NG     2        // batches per block; 512 blocks, 512 thr -> 2 blocks/CU
#define WROWS  928      // gx GEMM W rows padded

typedef __attribute__((ext_vector_type(8))) short short8;
typedef __attribute__((ext_vector_type(4))) float f32x4;

__device__ __forceinline__ float sigmoidf_(float x) {
    return 1.f / (1.f + __expf(-x));
}
__device__ __forceinline__ float ftanh(float x) {
    float e = __expf(2.f * x);
    return 1.f - 2.f / (e + 1.f);
}
__device__ __forceinline__ unsigned short f2bf(float f) {   // RNE f32->bf16
    uint32_t u = __float_as_uint(f);
    uint32_t r = u + 0x7FFFu + ((u >> 16) & 1u);
    return (unsigned short)(r >> 16);
}
__device__ __forceinline__ float bf2f(unsigned short h) {
    return __uint_as_float(((uint32_t)h) << 16);
}
__device__ __forceinline__ float bflo(uint32_t u) { return __uint_as_float(u << 16); }
__device__ __forceinline__ float bfhi(uint32_t u) { return __uint_as_float(u & 0xFFFF0000u); }

// ---- quad-pack recurrent weights (round-8 layout) --------------------------
__global__ __launch_bounds__(256) void convert_recQ(const float* __restrict__ W_hh,
                                                    const float* __restrict__ Wk,
                                                    uint4* __restrict__ Whh_q4,
                                                    uint2* __restrict__ Wk_q2) {
    int i = blockIdx.x * 256 + threadIdx.x;
    if (i < 50 * 400) {
        int jq = i / 400, p = i % 400;
        int j = jq * 4;
        const float* r0 = W_hh + (2 * p) * HDIM;
        const float* r1 = W_hh + (2 * p + 1) * HDIM;
        uint4 v;
        v.x = (uint32_t)f2bf(r0[j])     | ((uint32_t)f2bf(r0[j + 1]) << 16);
        v.y = (uint32_t)f2bf(r1[j])     | ((uint32_t)f2bf(r1[j + 1]) << 16);
        v.z = (uint32_t)f2bf(r0[j + 2]) | ((uint32_t)f2bf(r0[j + 3]) << 16);
        v.w = (uint32_t)f2bf(r1[j + 2]) | ((uint32_t)f2bf(r1[j + 3]) << 16);
        Whh_q4[i] = v;
    } else if (i < 50 * 400 + 50 * 160) {
        int e = i - 50 * 400;
        int jq = e / 160, col = e % 160;
        int j = jq * 4;
        const float* r = Wk + col * HDIM;
        uint2 v;
        v.x = (uint32_t)f2bf(r[j])     | ((uint32_t)f2bf(r[j + 1]) << 16);
        v.y = (uint32_t)f2bf(r[j + 2]) | ((uint32_t)f2bf(r[j + 3]) << 16);
        Wk_q2[e] = v;
    }
}

// ---------------- split f32 -> (hi, lo) bf16, zero-padded K (gx GEMM) ------
__global__ __launch_bounds__(256) void convert_A(const float* __restrict__ x,
                                                 unsigned short* __restrict__ Ahi,
                                                 unsigned short* __restrict__ Alo) {
    int c = blockIdx.x * 256 + threadIdx.x;
    int r = blockIdx.y;
    if (c >= KP) return;
    float v = (c < INDIM) ? x[(size_t)r * INDIM + c] : 0.f;
    unsigned short hi = f2bf(v);
    unsigned short lo = f2bf(v - bf2f(hi));
    size_t o = (size_t)r * KP + c;
    Ahi[o] = hi;
    Alo[o] = lo;
}

__global__ __launch_bounds__(256) void convert_W(const float* __restrict__ W_ih,
                                                 unsigned short* __restrict__ Wpk) {
    int c = blockIdx.x * 256 + threadIdx.x;
    int n = blockIdx.y;
    int sec = blockIdx.z;
    if (c >= KP) return;
    float v = (n < G4H && c < INDIM) ? W_ih[(size_t)n * INDIM + c] : 0.f;
    unsigned short hi = f2bf(v);
    size_t o = (size_t)sec * WROWS * KP + (size_t)n * KP + c;
    Wpk[o] = (sec == 0) ? hi : f2bf(v - bf2f(hi));
}

// ---------------- gx GEMM via 3-term split-bf16 MFMA ----------------------
__global__ __launch_bounds__(256) void gx_gemm_mfma(
        const unsigned short* __restrict__ Ahi,
        const unsigned short* __restrict__ Alo,
        const unsigned short* __restrict__ Wpk,
        const float* __restrict__ b_ih, const float* __restrict__ b_hh,
        float* __restrict__ gx) {
    __shared__ unsigned short Alds[128 * 64];
    __shared__ unsigned short Blds[128 * 64];
    const int tid = threadIdx.x;
    const int wv = tid >> 6, ln = tid & 63;
    const int wr = wv >> 1, wc = wv & 1;
    const int n0 = blockIdx.x * 128;
    const int m0 = blockIdx.y * 128;

    f32x4 acc[4][4];
#pragma unroll
    for (int m = 0; m < 4; ++m)
#pragma unroll
        for (int n = 0; n < 4; ++n) acc[m][n] = (f32x4){0.f, 0.f, 0.f, 0.f};

    int erow[4], ecol[4];
#pragma unroll
    for (int i = 0; i < 4; ++i) {
        int e = (i * 4 + wv) * 512 + ln * 8;
        erow[i] = e >> 6;
        ecol[i] = e & 63;
    }

    const unsigned short* Whi = Wpk;
    const unsigned short* Wlo = Wpk + (size_t)WROWS * KP;

#pragma unroll 1
    for (int s = 0; s < 3; ++s) {
        const unsigned short* Ab = ((s == 2) ? Alo : Ahi) + (size_t)m0 * KP;
        const unsigned short* Bb = ((s == 1) ? Wlo : Whi) + (size_t)n0 * KP;

        short8 ar[4], br[4];
#pragma unroll
        for (int i = 0; i < 4; ++i) {
            ar[i] = *(const short8*)&Ab[(size_t)erow[i] * KP + ecol[i]];
            br[i] = *(const short8*)&Bb[(size_t)erow[i] * KP + ecol[i]];
        }

#pragma unroll 1
        for (int k0 = 0; k0 < KP; k0 += 64) {
            __syncthreads();
#pragma unroll
            for (int i = 0; i < 4; ++i) {
                int e = (i * 4 + wv) * 512 + ln * 8;
                *(short8*)&Alds[e] = ar[i];
                *(short8*)&Blds[e] = br[i];
            }
            __syncthreads();
            if (k0 + 64 < KP) {
#pragma unroll
                for (int i = 0; i < 4; ++i) {
                    ar[i] = *(const short8*)&Ab[(size_t)erow[i] * KP + k0 + 64 + ecol[i]];
                    br[i] = *(const short8*)&Bb[(size_t)erow[i] * KP + k0 + 64 + ecol[i]];
                }
            }
#pragma unroll
            for (int ks = 0; ks < 2; ++ks) {
                short8 af[4], bf[4];
                int kcol = ks * 32 + (ln >> 4) * 8;
#pragma unroll
                for (int m = 0; m < 4; ++m) {
                    int row = wr * 64 + m * 16 + (ln & 15);
                    af[m] = *(const short8*)&Alds[row * 64 + kcol];
                }
#pragma unroll
                for (int n = 0; n < 4; ++n) {
                    int row = wc * 64 + n * 16 + (ln & 15);
                    bf[n] = *(const short8*)&Blds[row * 64 + kcol];
                }
#pragma unroll
                for (int m = 0; m < 4; ++m)
#pragma unroll
                    for (int n = 0; n < 4; ++n)
                        acc[m][n] = __builtin_amdgcn_mfma_f32_16x16x32_bf16(
                            af[m], bf[n], acc[m][n], 0, 0, 0);
            }
        }
    }

#pragma unroll
    for (int n = 0; n < 4; ++n) {
        int col = n0 + wc * 64 + n * 16 + (ln & 15);
        if (col >= G4H) continue;
        float bias = b_ih[col] + b_hh[col];
#pragma unroll
        for (int m = 0; m < 4; ++m) {
#pragma unroll
            for (int j = 0; j < 4; ++j) {
                int row = m0 + wr * 64 + m * 16 + (ln >> 4) * 4 + j;
                gx[(size_t)row * G4H + col] = acc[m][n][j] + bias;
            }
        }
    }
}

// ---------------- f32 fallback GEMM ---------------------------------------
__global__ __launch_bounds__(256) void gx_gemm(const float* __restrict__ x,
                                               const float* __restrict__ W_ih,
                                               const float* __restrict__ b_ih,
                                               const float* __restrict__ b_hh,
                                               float* __restrict__ gx) {
    const int BM = 128, BN = 80, BK = 16;
    __shared__ float As[BK][BM];
    __shared__ float Bs[BK][BN];
    int m0 = blockIdx.y * BM;
    int n0 = blockIdx.x * BN;
    int tid = threadIdx.x;
    int tm = tid >> 4, tn = tid & 15;
    float acc[8][5];
#pragma unroll
    for (int i = 0; i < 8; ++i)
#pragma unroll
        for (int j = 0; j < 5; ++j) acc[i][j] = 0.f;

    for (int k0 = 0; k0 < INDIM; k0 += BK) {
        {
            int row = tid >> 1, kk = (tid & 1) * 8;
            const float* ap = x + (size_t)(m0 + row) * INDIM + k0 + kk;
#pragma unroll
            for (int i = 0; i < 8; ++i)
                As[kk + i][row] = (k0 + kk + i < INDIM) ? ap[i] : 0.f;
        }
        if (tid < 160) {
            int col = tid >> 1, kk = (tid & 1) * 8;
            const float* bp = W_ih + (size_t)(n0 + col) * INDIM + k0 + kk;
#pragma unroll
            for (int i = 0; i < 8; ++i)
                Bs[kk + i][col] = (k0 + kk + i < INDIM) ? bp[i] : 0.f;
        }
        __syncthreads();
#pragma unroll
        for (int k = 0; k < BK; ++k) {
            float a[8], b[5];
#pragma unroll
            for (int i = 0; i < 8; ++i) a[i] = As[k][tm * 8 + i];
#pragma unroll
            for (int j = 0; j < 5; ++j) b[j] = Bs[k][tn * 5 + j];
#pragma unroll
            for (int i = 0; i < 8; ++i)
#pragma unroll
                for (int j = 0; j < 5; ++j) acc[i][j] += a[i] * b[j];
        }
        __syncthreads();
    }
#pragma unroll
    for (int j = 0; j < 5; ++j) {
        int n = n0 + tn * 5 + j;
        float bias = b_ih[n] + b_hh[n];
#pragma unroll
        for (int i = 0; i < 8; ++i) {
            int m = m0 + tm * 8 + i;
            gx[(size_t)m * G4H + n] = acc[i][j] + bias;
        }
    }
}

// ---------------- persistent NTM scan: NG=2, 512 thr, 5 barriers/step ------
__global__ __launch_bounds__(512, 4) void ntm_scan(
        const float* __restrict__ gx,          // [T][B][800]
        const uint4* __restrict__ Whh_q4,      // [50][400] quad-packed bf16
        const uint2* __restrict__ Wk_q2,       // [50][160] quad-packed bf16
        const float* __restrict__ bk,
        const float* __restrict__ Wsm,         // [4][200]
        const float* __restrict__ bs,
        const float* __restrict__ Wo,          // [5][360]
        const float* __restrict__ bo,
        float* __restrict__ out) {             // [T][B][5]
    __shared__ float sM[NG][NMEM][DPAD];
    __shared__ float sh[NG][HDIM];
    __shared__ float sgate[NG][G4H];
    __shared__ float swr[NG][RH][NMEM];
    __shared__ float sww[NG][RH][NMEM];
    __shared__ float sKs[NG][RH][NMEM];
    __shared__ float swlu[NG][NMEM];
    __shared__ float sk[NG][RH][DMEM];
    __shared__ float sr[NG][RD];
    __shared__ float snk[NG][RH];
    __shared__ float ssig[NG][RH];
    __shared__ float snM[NG][NMEM];
    __shared__ int   sidx[NG];

    const int tid = threadIdx.x;
    const int b0  = blockIdx.x * NG;
    const int w   = tid >> 6, l = tid & 63;

    // ---- init carries ----
    for (int e = tid; e < NG * NMEM * DPAD; e += 512) ((float*)sM)[e] = 0.f;
    for (int e = tid; e < NG * HDIM; e += 512) ((float*)sh)[e] = 0.f;
    for (int e = tid; e < NG * RH * NMEM; e += 512) ((float*)swr)[e] = 0.f;
    for (int e = tid; e < NG * NMEM; e += 512) ((float*)swlu)[e] = 1.f;

    float c_reg = 0.f;
    float gxr0 = 0.f, gxr1 = 0.f, gxr2 = 0.f, gxr3 = 0.f;
    int pg = 0, pj = 0;
    if (tid < NG * HDIM) {
        pg = tid / HDIM; pj = tid - pg * HDIM;
        const float* gxp = gx + (size_t)(b0 + pg) * G4H + pj;
        gxr0 = gxp[0]; gxr1 = gxp[HDIM]; gxr2 = gxp[2 * HDIM]; gxr3 = gxp[3 * HDIM];
    }
    // wave-7 register-resident usage: lane (hg=l>>5, hl=l&31) owns wu[g=hg][hl+32k]
    float wu_reg0 = 0.f, wu_reg1 = 0.f, wu_reg2 = 0.f, wu_reg3 = 0.f;
    __syncthreads();

    // half-wave (32-lane) output head for group g, step tt; reads sh, sr
    auto head_half = [&](int g, int tt) {
        const int hl = l & 31;
        float v[NWAY];
#pragma unroll
        for (int o = 0; o < NWAY; ++o) {
            const float* wrow = Wo + o * (HDIM + RD);
            float acc = 0.f;
            for (int j = hl; j < HDIM; j += 32) acc += sh[g][j] * wrow[j];
            for (int d = hl; d < RD; d += 32) acc += sr[g][d] * wrow[HDIM + d];
#pragma unroll
            for (int off = 16; off; off >>= 1) acc += __shfl_xor(acc, off);
            v[o] = acc + bo[o];
        }
        if (hl == 0) {
            float mx = -1e30f;
#pragma unroll
            for (int o = 0; o < NWAY; ++o) { v[o] = sigmoidf_(v[o]); mx = fmaxf(mx, v[o]); }
            float s = 0.f;
#pragma unroll
            for (int o = 0; o < NWAY; ++o) { v[o] = __expf(v[o] - mx); s += v[o]; }
            float inv = 1.f / s;
            float* op = out + ((size_t)tt * BATCH + (b0 + g)) * NWAY;
#pragma unroll
            for (int o = 0; o < NWAY; ++o) op[o] = v[o] * inv;
        }
    };

    for (int t = 0; t < TSTEPS; ++t) {
        // ==== A: gates GEMV (thr 0-399) | wave 7 (split halves per g):
        //         head(t-1) + wu-update(reg) + argmin + kth + wlu ====
        if (tid < 400) {
            const uint4* wq = Whh_q4 + tid;
            float a00 = 0.f, a01 = 0.f, a10 = 0.f, a11 = 0.f;
#pragma unroll 5
            for (int jq = 0; jq < 50; ++jq) {
                uint4 wv = wq[jq * 400];
                float4 h0 = *(const float4*)&sh[0][jq * 4];
                float4 h1 = *(const float4*)&sh[1][jq * 4];
                float we0 = bflo(wv.x), we1 = bfhi(wv.x);
                float wo0 = bflo(wv.y), wo1 = bfhi(wv.y);
                float we2 = bflo(wv.z), we3 = bfhi(wv.z);
                float wo2 = bflo(wv.w), wo3 = bfhi(wv.w);
                a00 += we0 * h0.x + we1 * h0.y + we2 * h0.z + we3 * h0.w;
                a01 += wo0 * h0.x + wo1 * h0.y + wo2 * h0.z + wo3 * h0.w;
                a10 += we0 * h1.x + we1 * h1.y + we2 * h1.z + we3 * h1.w;
                a11 += wo0 * h1.x + wo1 * h1.y + wo2 * h1.z + wo3 * h1.w;
            }
            sgate[0][2 * tid]     = a00;
            sgate[0][2 * tid + 1] = a01;
            sgate[1][2 * tid]     = a10;
            sgate[1][2 * tid + 1] = a11;
        } else if (w == 7) {
            const int hg = l >> 5;     // lanes 0-31 -> g0, 32-63 -> g1
            const int hl = l & 31;
            if (t > 0) {
                head_half(hg, t - 1);
                // usage update in registers (same per-r order as before)
#pragma unroll
                for (int k = 0; k < 4; ++k) {
                    int m = hl + 32 * k;
                    float wu = GAMMA_ * ((k == 0) ? wu_reg0 : (k == 1) ? wu_reg1
                                         : (k == 2) ? wu_reg2 : wu_reg3);
#pragma unroll
                    for (int r = 0; r < RH; ++r) wu += swr[hg][r][m] + sww[hg][r][m];
                    if (k == 0) wu_reg0 = wu; else if (k == 1) wu_reg1 = wu;
                    else if (k == 2) wu_reg2 = wu; else wu_reg3 = wu;
                }
            }
            // argmin (first-index ties) over 128 via 32 lanes x 4
            {
                float mv = wu_reg0; int mi = hl;
                if (wu_reg1 < mv) { mv = wu_reg1; mi = hl + 32; }
                if (wu_reg2 < mv) { mv = wu_reg2; mi = hl + 64; }
                if (wu_reg3 < mv) { mv = wu_reg3; mi = hl + 96; }
#pragma unroll
                for (int off = 16; off; off >>= 1) {
                    float ov = __shfl_xor(mv, off);
                    int   oi = __shfl_xor(mi, off);
                    if (ov < mv || (ov == mv && oi < mi)) { mv = ov; mi = oi; }
                }
                if (hl == 0) sidx[hg] = mi;
            }
            // kth-smallest (value invariant to tie-break) + wlu
            {
                float v0 = wu_reg0, v1 = wu_reg1, v2 = wu_reg2, v3 = wu_reg3;
                float kth = 0.f;
#pragma unroll
                for (int it = 0; it < RH; ++it) {
                    float mv = v0; int mi = hl;
                    if (v1 < mv) { mv = v1; mi = hl + 32; }
                    if (v2 < mv) { mv = v2; mi = hl + 64; }
                    if (v3 < mv) { mv = v3; mi = hl + 96; }
                    for (int off = 16; off; off >>= 1) {
                        float ov = __shfl_xor(mv, off);
                        int   oi = __shfl_xor(mi, off);
                        if (ov < mv || (ov == mv && oi < mi)) { mv = ov; mi = oi; }
                    }
                    kth = mv;
                    if (mi == hl) v0 = __builtin_inff();
                    else if (mi == hl + 32) v1 = __builtin_inff();
                    else if (mi == hl + 64) v2 = __builtin_inff();
                    else v3 = (mi == hl + 96) ? __builtin_inff() : v3;
                }
                swlu[hg][hl]      = (wu_reg0 <= kth) ? 1.f : 0.f;
                swlu[hg][hl + 32] = (wu_reg1 <= kth) ? 1.f : 0.f;
                swlu[hg][hl + 64] = (wu_reg2 <= kth) ? 1.f : 0.f;
                swlu[hg][hl + 96] = (wu_reg3 <= kth) ? 1.f : 0.f;
            }
        }
        __syncthreads();

        // ==== B: LSTM cell (400 thr); c in regs; prefetch next gx ====
        if (tid < NG * HDIM) {
            float ig = sigmoidf_(sgate[pg][pj] + gxr0);
            float fg = sigmoidf_(sgate[pg][pj + HDIM] + gxr1);
            float gv = ftanh(sgate[pg][pj + 2 * HDIM] + gxr2);
            float og = sigmoidf_(sgate[pg][pj + 3 * HDIM] + gxr3);
            c_reg = fg * c_reg + ig * gv;
            sh[pg][pj] = og * ftanh(c_reg);
            if (t + 1 < TSTEPS) {
                const float* gxp = gx + ((size_t)(t + 1) * BATCH + b0 + pg) * G4H + pj;
                gxr0 = gxp[0]; gxr1 = gxp[HDIM]; gxr2 = gxp[2 * HDIM]; gxr3 = gxp[3 * HDIM];
            }
        }
        __syncthreads();

        // ==== C (fused w/ D): keys full-K (320 thr) | sigma via shfl (32 thr) ====
        if (tid < 320) {
            int g = tid / 160, col = tid - (tid / 160) * 160;
            const uint2* wq = Wk_q2 + col;
            float a = 0.f;
#pragma unroll 5
            for (int q = 0; q < 50; ++q) {
                uint2 wv = wq[q * RD];
                float4 h = *(const float4*)&sh[g][q * 4];
                a += bflo(wv.x) * h.x + bfhi(wv.x) * h.y
                   + bflo(wv.y) * h.z + bfhi(wv.y) * h.w;
            }
            sk[g][col / DMEM][col % DMEM] = ftanh(a + bk[col]);
        } else if (tid < 352) {
            int v = tid - 320; int g = v >> 4, rc = v & 15, r = rc >> 2, cc = rc & 3;
            const float* wrow = Wsm + r * HDIM;
            float a = 0.f;
            for (int j = 50 * cc; j < 50 * cc + 50; ++j) a += sh[g][j] * wrow[j];
            a += __shfl_xor(a, 1);
            a += __shfl_xor(a, 2);
            if (cc == 0) ssig[g][r] = sigmoidf_(ftanh(a + bs[r]));
        }
        __syncthreads();

        // ==== E2'+NF fused: ww, zero-LU-row, M update, cosine dots, norms ====
        if (tid < 256) {
            int g = tid >> 7, m = tid & 127;
            float sg0 = ssig[g][0], sg1 = ssig[g][1], sg2 = ssig[g][2], sg3 = ssig[g][3];
            float wl = swlu[g][m];
            float w0 = sg0 * swr[g][0][m] + (1.f - sg0) * wl;
            float w1 = sg1 * swr[g][1][m] + (1.f - sg1) * wl;
            float w2 = sg2 * swr[g][2][m] + (1.f - sg2) * wl;
            float w3 = sg3 * swr[g][3][m] + (1.f - sg3) * wl;
            sww[g][0][m] = w0; sww[g][1][m] = w1;
            sww[g][2][m] = w2; sww[g][3][m] = w3;
            bool zr = (m == sidx[g]);
            float d0 = 0.f, d1 = 0.f, d2 = 0.f, d3 = 0.f, nn = 0.f;
#pragma unroll
            for (int q = 0; q < 10; ++q) {
                int d = q * 4;
                float4 mv = *(const float4*)&sM[g][m][d];
                float4 k0 = *(const float4*)&sk[g][0][d];
                float4 k1 = *(const float4*)&sk[g][1][d];
                float4 k2 = *(const float4*)&sk[g][2][d];
                float4 k3 = *(const float4*)&sk[g][3][d];
                float4 o;
                o.x = (zr ? 0.f : mv.x) + w0 * k0.x + w1 * k1.x + w2 * k2.x + w3 * k3.x;
                o.y = (zr ? 0.f : mv.y) + w0 * k0.y + w1 * k1.y + w2 * k2.y + w3 * k3.y;
                o.z = (zr ? 0.f : mv.z) + w0 * k0.z + w1 * k1.z + w2 * k2.z + w3 * k3.z;
                o.w = (zr ? 0.f : mv.w) + w0 * k0.w + w1 * k1.w + w2 * k2.w + w3 * k3.w;
                *(float4*)&sM[g][m][d] = o;
                d0 += k0.x * o.x + k0.y * o.y + k0.z * o.z + k0.w * o.w;
                d1 += k1.x * o.x + k1.y * o.y + k1.z * o.z + k1.w * o.w;
                d2 += k2.x * o.x + k2.y * o.y + k2.z * o.z + k2.w * o.w;
                d3 += k3.x * o.x + k3.y * o.y + k3.z * o.z + k3.w * o.w;
                nn += o.x * o.x + o.y * o.y + o.z * o.z + o.w * o.w;
            }
            sKs[g][0][m] = d0; sKs[g][1][m] = d1;
            sKs[g][2][m] = d2; sKs[g][3][m] = d3;
            snM[g][m] = sqrtf(nn);
        } else if (tid < 264) {
            int v = tid - 256; int g2 = v >> 2, r2 = v & 3;
            float a0 = 0.f, a1 = 0.f, a2 = 0.f, a3 = 0.f;
#pragma unroll
            for (int q = 0; q < 10; ++q) {
                float4 kv = *(const float4*)&sk[g2][r2][q * 4];
                a0 += kv.x * kv.x; a1 += kv.y * kv.y;
                a2 += kv.z * kv.z; a3 += kv.w * kv.w;
            }
            snk[g2][r2] = sqrtf((a0 + a1) + (a2 + a3));
        }
        __syncthreads();

        // ==== G+H fused: softmax -> swr -> same-wave read-vector slice ====
        {
            int g = w >> 2, r = w & 3;
            float ink = snk[g][r];
            float a = sKs[g][r][l] / (ink * snM[g][l]);
            float b = sKs[g][r][l + 64] / (ink * snM[g][l + 64]);
            float mx = fmaxf(a, b);
#pragma unroll
            for (int off = 32; off; off >>= 1) mx = fmaxf(mx, __shfl_xor(mx, off));
            float ea = __expf(a - mx), eb = __expf(b - mx);
            float s = ea + eb;
#pragma unroll
            for (int off = 32; off; off >>= 1) s += __shfl_xor(s, off);
            float inv = 1.f / s;
            swr[g][r][l]      = ea * inv;
            swr[g][r][l + 64] = eb * inv;
            // read vector slice for this (g,r): 10 d4-slots x 2 m-halves
            int d4 = l & 31;
            if (d4 < 10) {
                int mb = (l >> 5) * 64;
                float a0 = 0.f, a1 = 0.f, a2 = 0.f, a3 = 0.f;
                for (int m = mb; m < mb + 64; ++m) {
                    float wv = swr[g][r][m];
                    float4 mv = *(const float4*)&sM[g][m][d4 * 4];
                    a0 += wv * mv.x; a1 += wv * mv.y;
                    a2 += wv * mv.z; a3 += wv * mv.w;
                }
                a0 += __shfl_xor(a0, 32);
                a1 += __shfl_xor(a1, 32);
                a2 += __shfl_xor(a2, 32);
                a3 += __shfl_xor(a3, 32);
                if (l < 10) {
                    float4 res = {a0, a1, a2, a3};
                    *(float4*)&sr[g][r * DMEM + d4 * 4] = res;
                }
            }
        }
        __syncthreads();
    }

    // ---- epilogue: head for the final step (both halves of wave 7) ----
    if (w == 7) head_half(l >> 5, TSTEPS - 1);
}

extern "C" void kernel_launch(void* const* d_in, const int* in_sizes, int n_in,
                              void* d_out, int out_size, void* d_ws, size_t ws_size,
                              hipStream_t stream) {
    const float* x    = (const float*)d_in[0];
    const float* W_ih = (const float*)d_in[1];
    const float* W_hh = (const float*)d_in[2];
    const float* b_ih = (const float*)d_in[3];
    const float* b_hh = (const float*)d_in[4];
    const float* Wk   = (const float*)d_in[5];
    const float* bk   = (const float*)d_in[6];
    const float* Wsm  = (const float*)d_in[7];
    const float* bs   = (const float*)d_in[8];
    const float* Wo   = (const float*)d_in[9];
    const float* bo   = (const float*)d_in[10];
    float* out = (float*)d_out;

    const size_t gx_elems  = (size_t)TSTEPS * BATCH * G4H;  // 40,960,000 f32
    const size_t whh_q4_e  = (size_t)50 * 400;              // uint4 (16B)
    const size_t wk_q2_e   = (size_t)50 * 160;              // uint2 (8B)
    const size_t a_elems   = (size_t)TSTEPS * BATCH * KP;   // u16 each
    const size_t w_elems   = (size_t)2 * WROWS * KP;        // u16
    const size_t need_base = gx_elems * 4 + whh_q4_e * 16 + wk_q2_e * 8;
    const size_t need_mfma = need_base + (2 * a_elems + w_elems) * 2;
    if (ws_size < need_base) return;

    float* gxb = (float*)d_ws;
    uint4* Whh_q4 = (uint4*)(gxb + gx_elems);
    uint2* Wk_q2  = (uint2*)(Whh_q4 + whh_q4_e);

    {
        int tot = (int)(whh_q4_e + wk_q2_e);
        convert_recQ<<<dim3((tot + 255) / 256), dim3(256), 0, stream>>>(W_hh, Wk, Whh_q4, Wk_q2);
    }

    if (ws_size >= need_mfma) {
        unsigned short* Ahi = (unsigned short*)(Wk_q2 + wk_q2_e);
        unsigned short* Alo = Ahi + a_elems;
        unsigned short* Wpk = Alo + a_elems;
        convert_A<<<dim3(2, TSTEPS * BATCH), dim3(256), 0, stream>>>(x, Ahi, Alo);
        convert_W<<<dim3(2, WROWS, 2), dim3(256), 0, stream>>>(W_ih, Wpk);
        gx_gemm_mfma<<<dim3(7, (TSTEPS * BATCH) / 128), dim3(256), 0, stream>>>(
            Ahi, Alo, Wpk, b_ih, b_hh, gxb);
    } else {
        gx_gemm<<<dim3(G4H / 80, (TSTEPS * BATCH) / 128), dim3(256), 0, stream>>>(
            x, W_ih, b_ih, b_hh, gxb);
    }

    ntm_scan<<<dim3(BATCH / NG), dim3(512), 0, stream>>>(
        gxb, Whh_q4, Wk_q2, bk, Wsm, bs, Wo, bo, out);
}

// Round 13
// 1359.488 us; speedup vs baseline: 1.3257x; 1.1465x over previous
//
#include <hip/hip_runtime.h>
#include <stdint.h>

#define TSTEPS 50
#define BATCH  1024
#define INDIM  405
#define KP     448      // padded K for gx GEMM (7 x 64)
#define HDIM   200
#define G4H    800      // 4*H
#define NMEM   128
#define DMEM   40
#define DPAD   44       // sM row stride: 16B-aligned
#define RH     4
#define RD     160      // RH*DMEM
#define NWAY   5
#define GAMMA_ 0.99f
#define NG     2        // batches per block; 512 blocks, 512 thr -> 2 blocks/CU
#define WROWS  928      // gx GEMM W rows padded

typedef __attribute__((ext_vector_type(8))) short short8;
typedef __attribute__((ext_vector_type(4))) float f32x4;
typedef _Float16 h2 __attribute__((ext_vector_type(2)));

__device__ __forceinline__ float sigmoidf_(float x) {
    return 1.f / (1.f + __expf(-x));
}
__device__ __forceinline__ float ftanh(float x) {
    float e = __expf(2.f * x);
    return 1.f - 2.f / (e + 1.f);
}
__device__ __forceinline__ unsigned short f2bf(float f) {   // RNE f32->bf16
    uint32_t u = __float_as_uint(f);
    uint32_t r = u + 0x7FFFu + ((u >> 16) & 1u);
    return (unsigned short)(r >> 16);
}
__device__ __forceinline__ float bf2f(unsigned short h) {
    return __uint_as_float(((uint32_t)h) << 16);
}
__device__ __forceinline__ h2 u2h(uint32_t u) {
    union { uint32_t u; h2 h; } c; c.u = u; return c.h;
}
// 2-term f16 dot with f32 accumulate (v_dot2_f32_f16 when available)
__device__ __forceinline__ float fdot2_(uint32_t w, uint32_t h, float acc) {
#if __has_builtin(__builtin_amdgcn_fdot2)
    return __builtin_amdgcn_fdot2(u2h(w), u2h(h), acc, false);
#else
    union { uint32_t u; _Float16 f[2]; } cw, ch;
    cw.u = w; ch.u = h;
    return acc + (float)cw.f[0] * (float)ch.f[0] + (float)cw.f[1] * (float)ch.f[1];
#endif
}
__device__ __forceinline__ uint32_t pkh(float a, float b) {  // pack 2 f32 -> f16x2
    union { _Float16 f[2]; uint32_t u; } c;
    c.f[0] = (_Float16)a; c.f[1] = (_Float16)b; return c.u;
}

// ---- quad-pack recurrent weights as f16 pairs (round-8 index layout) -------
__global__ __launch_bounds__(256) void convert_recQ(const float* __restrict__ W_hh,
                                                    const float* __restrict__ Wk,
                                                    uint4* __restrict__ Whh_q4,
                                                    uint2* __restrict__ Wk_q2) {
    int i = blockIdx.x * 256 + threadIdx.x;
    if (i < 50 * 400) {
        int jq = i / 400, p = i % 400;
        int j = jq * 4;
        const float* r0 = W_hh + (2 * p) * HDIM;
        const float* r1 = W_hh + (2 * p + 1) * HDIM;
        uint4 v;
        v.x = pkh(r0[j],     r0[j + 1]);
        v.y = pkh(r1[j],     r1[j + 1]);
        v.z = pkh(r0[j + 2], r0[j + 3]);
        v.w = pkh(r1[j + 2], r1[j + 3]);
        Whh_q4[i] = v;
    } else if (i < 50 * 400 + 50 * 160) {
        int e = i - 50 * 400;
        int jq = e / 160, col = e % 160;
        int j = jq * 4;
        const float* r = Wk + col * HDIM;
        uint2 v;
        v.x = pkh(r[j],     r[j + 1]);
        v.y = pkh(r[j + 2], r[j + 3]);
        Wk_q2[e] = v;
    }
}

// ---------------- split f32 -> (hi, lo) bf16, zero-padded K (gx GEMM) ------
__global__ __launch_bounds__(256) void convert_A(const float* __restrict__ x,
                                                 unsigned short* __restrict__ Ahi,
                                                 unsigned short* __restrict__ Alo) {
    int c = blockIdx.x * 256 + threadIdx.x;
    int r = blockIdx.y;
    if (c >= KP) return;
    float v = (c < INDIM) ? x[(size_t)r * INDIM + c] : 0.f;
    unsigned short hi = f2bf(v);
    unsigned short lo = f2bf(v - bf2f(hi));
    size_t o = (size_t)r * KP + c;
    Ahi[o] = hi;
    Alo[o] = lo;
}

__global__ __launch_bounds__(256) void convert_W(const float* __restrict__ W_ih,
                                                 unsigned short* __restrict__ Wpk) {
    int c = blockIdx.x * 256 + threadIdx.x;
    int n = blockIdx.y;
    int sec = blockIdx.z;
    if (c >= KP) return;
    float v = (n < G4H && c < INDIM) ? W_ih[(size_t)n * INDIM + c] : 0.f;
    unsigned short hi = f2bf(v);
    size_t o = (size_t)sec * WROWS * KP + (size_t)n * KP + c;
    Wpk[o] = (sec == 0) ? hi : f2bf(v - bf2f(hi));
}

// ---------------- gx GEMM via 3-term split-bf16 MFMA ----------------------
__global__ __launch_bounds__(256) void gx_gemm_mfma(
        const unsigned short* __restrict__ Ahi,
        const unsigned short* __restrict__ Alo,
        const unsigned short* __restrict__ Wpk,
        const float* __restrict__ b_ih, const float* __restrict__ b_hh,
        float* __restrict__ gx) {
    __shared__ unsigned short Alds[128 * 64];
    __shared__ unsigned short Blds[128 * 64];
    const int tid = threadIdx.x;
    const int wv = tid >> 6, ln = tid & 63;
    const int wr = wv >> 1, wc = wv & 1;
    const int n0 = blockIdx.x * 128;
    const int m0 = blockIdx.y * 128;

    f32x4 acc[4][4];
#pragma unroll
    for (int m = 0; m < 4; ++m)
#pragma unroll
        for (int n = 0; n < 4; ++n) acc[m][n] = (f32x4){0.f, 0.f, 0.f, 0.f};

    int erow[4], ecol[4];
#pragma unroll
    for (int i = 0; i < 4; ++i) {
        int e = (i * 4 + wv) * 512 + ln * 8;
        erow[i] = e >> 6;
        ecol[i] = e & 63;
    }

    const unsigned short* Whi = Wpk;
    const unsigned short* Wlo = Wpk + (size_t)WROWS * KP;

#pragma unroll 1
    for (int s = 0; s < 3; ++s) {
        const unsigned short* Ab = ((s == 2) ? Alo : Ahi) + (size_t)m0 * KP;
        const unsigned short* Bb = ((s == 1) ? Wlo : Whi) + (size_t)n0 * KP;

        short8 ar[4], br[4];
#pragma unroll
        for (int i = 0; i < 4; ++i) {
            ar[i] = *(const short8*)&Ab[(size_t)erow[i] * KP + ecol[i]];
            br[i] = *(const short8*)&Bb[(size_t)erow[i] * KP + ecol[i]];
        }

#pragma unroll 1
        for (int k0 = 0; k0 < KP; k0 += 64) {
            __syncthreads();
#pragma unroll
            for (int i = 0; i < 4; ++i) {
                int e = (i * 4 + wv) * 512 + ln * 8;
                *(short8*)&Alds[e] = ar[i];
                *(short8*)&Blds[e] = br[i];
            }
            __syncthreads();
            if (k0 + 64 < KP) {
#pragma unroll
                for (int i = 0; i < 4; ++i) {
                    ar[i] = *(const short8*)&Ab[(size_t)erow[i] * KP + k0 + 64 + ecol[i]];
                    br[i] = *(const short8*)&Bb[(size_t)erow[i] * KP + k0 + 64 + ecol[i]];
                }
            }
#pragma unroll
            for (int ks = 0; ks < 2; ++ks) {
                short8 af[4], bf[4];
                int kcol = ks * 32 + (ln >> 4) * 8;
#pragma unroll
                for (int m = 0; m < 4; ++m) {
                    int row = wr * 64 + m * 16 + (ln & 15);
                    af[m] = *(const short8*)&Alds[row * 64 + kcol];
                }
#pragma unroll
                for (int n = 0; n < 4; ++n) {
                    int row = wc * 64 + n * 16 + (ln & 15);
                    bf[n] = *(const short8*)&Blds[row * 64 + kcol];
                }
#pragma unroll
                for (int m = 0; m < 4; ++m)
#pragma unroll
                    for (int n = 0; n < 4; ++n)
                        acc[m][n] = __builtin_amdgcn_mfma_f32_16x16x32_bf16(
                            af[m], bf[n], acc[m][n], 0, 0, 0);
            }
        }
    }

#pragma unroll
    for (int n = 0; n < 4; ++n) {
        int col = n0 + wc * 64 + n * 16 + (ln & 15);
        if (col >= G4H) continue;
        float bias = b_ih[col] + b_hh[col];
#pragma unroll
        for (int m = 0; m < 4; ++m) {
#pragma unroll
            for (int j = 0; j < 4; ++j) {
                int row = m0 + wr * 64 + m * 16 + (ln >> 4) * 4 + j;
                gx[(size_t)row * G4H + col] = acc[m][n][j] + bias;
            }
        }
    }
}

// ---------------- f32 fallback GEMM ---------------------------------------
__global__ __launch_bounds__(256) void gx_gemm(const float* __restrict__ x,
                                               const float* __restrict__ W_ih,
                                               const float* __restrict__ b_ih,
                                               const float* __restrict__ b_hh,
                                               float* __restrict__ gx) {
    const int BM = 128, BN = 80, BK = 16;
    __shared__ float As[BK][BM];
    __shared__ float Bs[BK][BN];
    int m0 = blockIdx.y * BM;
    int n0 = blockIdx.x * BN;
    int tid = threadIdx.x;
    int tm = tid >> 4, tn = tid & 15;
    float acc[8][5];
#pragma unroll
    for (int i = 0; i < 8; ++i)
#pragma unroll
        for (int j = 0; j < 5; ++j) acc[i][j] = 0.f;

    for (int k0 = 0; k0 < INDIM; k0 += BK) {
        {
            int row = tid >> 1, kk = (tid & 1) * 8;
            const float* ap = x + (size_t)(m0 + row) * INDIM + k0 + kk;
#pragma unroll
            for (int i = 0; i < 8; ++i)
                As[kk + i][row] = (k0 + kk + i < INDIM) ? ap[i] : 0.f;
        }
        if (tid < 160) {
            int col = tid >> 1, kk = (tid & 1) * 8;
            const float* bp = W_ih + (size_t)(n0 + col) * INDIM + k0 + kk;
#pragma unroll
            for (int i = 0; i < 8; ++i)
                Bs[kk + i][col] = (k0 + kk + i < INDIM) ? bp[i] : 0.f;
        }
        __syncthreads();
#pragma unroll
        for (int k = 0; k < BK; ++k) {
            float a[8], b[5];
#pragma unroll
            for (int i = 0; i < 8; ++i) a[i] = As[k][tm * 8 + i];
#pragma unroll
            for (int j = 0; j < 5; ++j) b[j] = Bs[k][tn * 5 + j];
#pragma unroll
            for (int i = 0; i < 8; ++i)
#pragma unroll
                for (int j = 0; j < 5; ++j) acc[i][j] += a[i] * b[j];
        }
        __syncthreads();
    }
#pragma unroll
    for (int j = 0; j < 5; ++j) {
        int n = n0 + tn * 5 + j;
        float bias = b_ih[n] + b_hh[n];
#pragma unroll
        for (int i = 0; i < 8; ++i) {
            int m = m0 + tm * 8 + i;
            gx[(size_t)m * G4H + n] = acc[i][j] + bias;
        }
    }
}

// ---------------- persistent NTM scan: NG=2, 512 thr, 5 barriers/step ------
__global__ __launch_bounds__(512, 4) void ntm_scan(
        const float* __restrict__ gx,          // [T][B][800]
        const uint4* __restrict__ Whh_q4,      // [50][400] quad-packed f16
        const uint2* __restrict__ Wk_q2,       // [50][160] quad-packed f16
        const float* __restrict__ bk,
        const float* __restrict__ Wsm,         // [4][200]
        const float* __restrict__ bs,
        const float* __restrict__ Wo,          // [5][360]
        const float* __restrict__ bo,
        float* __restrict__ out) {             // [T][B][5]
    __shared__ float sM[NG][NMEM][DPAD];
    __shared__ float sh[NG][HDIM];
    __shared__ _Float16 shh[NG][HDIM];         // f16 mirror of h for dot2
    __shared__ float sgate[NG][G4H];
    __shared__ float swr[NG][RH][NMEM];
    __shared__ float sww[NG][RH][NMEM];
    __shared__ float sKs[NG][RH][NMEM];
    __shared__ float swlu[NG][NMEM];
    __shared__ float sk[NG][RH][DMEM];
    __shared__ float sr[NG][RD];
    __shared__ float snk[NG][RH];
    __shared__ float ssig[NG][RH];
    __shared__ float snM[NG][NMEM];
    __shared__ int   sidx[NG];

    const int tid = threadIdx.x;
    const int b0  = blockIdx.x * NG;
    const int w   = tid >> 6, l = tid & 63;

    // ---- init carries ----
    for (int e = tid; e < NG * NMEM * DPAD; e += 512) ((float*)sM)[e] = 0.f;
    for (int e = tid; e < NG * HDIM; e += 512) { ((float*)sh)[e] = 0.f; ((_Float16*)shh)[e] = (_Float16)0.f; }
    for (int e = tid; e < NG * RH * NMEM; e += 512) ((float*)swr)[e] = 0.f;
    for (int e = tid; e < NG * NMEM; e += 512) ((float*)swlu)[e] = 1.f;

    float c_reg = 0.f;
    float gxr0 = 0.f, gxr1 = 0.f, gxr2 = 0.f, gxr3 = 0.f;
    int pg = 0, pj = 0;
    if (tid < NG * HDIM) {
        pg = tid / HDIM; pj = tid - pg * HDIM;
        const float* gxp = gx + (size_t)(b0 + pg) * G4H + pj;
        gxr0 = gxp[0]; gxr1 = gxp[HDIM]; gxr2 = gxp[2 * HDIM]; gxr3 = gxp[3 * HDIM];
    }
    // wave-7 register-resident usage: lane (hg=l>>5, hl=l&31) owns wu[g=hg][hl+32k]
    float wu_reg0 = 0.f, wu_reg1 = 0.f, wu_reg2 = 0.f, wu_reg3 = 0.f;
    __syncthreads();

    // half-wave (32-lane) output head for group g, step tt; reads sh, sr
    auto head_half = [&](int g, int tt) {
        const int hl = l & 31;
        float v[NWAY];
#pragma unroll
        for (int o = 0; o < NWAY; ++o) {
            const float* wrow = Wo + o * (HDIM + RD);
            float acc = 0.f;
            for (int j = hl; j < HDIM; j += 32) acc += sh[g][j] * wrow[j];
            for (int d = hl; d < RD; d += 32) acc += sr[g][d] * wrow[HDIM + d];
#pragma unroll
            for (int off = 16; off; off >>= 1) acc += __shfl_xor(acc, off);
            v[o] = acc + bo[o];
        }
        if (hl == 0) {
            float mx = -1e30f;
#pragma unroll
            for (int o = 0; o < NWAY; ++o) { v[o] = sigmoidf_(v[o]); mx = fmaxf(mx, v[o]); }
            float s = 0.f;
#pragma unroll
            for (int o = 0; o < NWAY; ++o) { v[o] = __expf(v[o] - mx); s += v[o]; }
            float inv = 1.f / s;
            float* op = out + ((size_t)tt * BATCH + (b0 + g)) * NWAY;
#pragma unroll
            for (int o = 0; o < NWAY; ++o) op[o] = v[o] * inv;
        }
    };

    for (int t = 0; t < TSTEPS; ++t) {
        // ==== A: gates GEMV via fdot2 (thr 0-399) | wave 7 aux ====
        if (tid < 400) {
            const uint4* wq = Whh_q4 + tid;
            float a00 = 0.f, a01 = 0.f, a10 = 0.f, a11 = 0.f;
#pragma unroll 5
            for (int jq = 0; jq < 50; ++jq) {
                uint4 wv = wq[jq * 400];
                uint2 hp0 = *(const uint2*)&shh[0][jq * 4];
                uint2 hp1 = *(const uint2*)&shh[1][jq * 4];
                a00 = fdot2_(wv.x, hp0.x, a00);
                a00 = fdot2_(wv.z, hp0.y, a00);
                a01 = fdot2_(wv.y, hp0.x, a01);
                a01 = fdot2_(wv.w, hp0.y, a01);
                a10 = fdot2_(wv.x, hp1.x, a10);
                a10 = fdot2_(wv.z, hp1.y, a10);
                a11 = fdot2_(wv.y, hp1.x, a11);
                a11 = fdot2_(wv.w, hp1.y, a11);
            }
            sgate[0][2 * tid]     = a00;
            sgate[0][2 * tid + 1] = a01;
            sgate[1][2 * tid]     = a10;
            sgate[1][2 * tid + 1] = a11;
        } else if (w == 7) {
            const int hg = l >> 5;     // lanes 0-31 -> g0, 32-63 -> g1
            const int hl = l & 31;
            if (t > 0) {
                head_half(hg, t - 1);
                // usage update in registers (same per-r order as before)
#pragma unroll
                for (int k = 0; k < 4; ++k) {
                    int m = hl + 32 * k;
                    float wu = GAMMA_ * ((k == 0) ? wu_reg0 : (k == 1) ? wu_reg1
                                         : (k == 2) ? wu_reg2 : wu_reg3);
#pragma unroll
                    for (int r = 0; r < RH; ++r) wu += swr[hg][r][m] + sww[hg][r][m];
                    if (k == 0) wu_reg0 = wu; else if (k == 1) wu_reg1 = wu;
                    else if (k == 2) wu_reg2 = wu; else wu_reg3 = wu;
                }
            }
            // argmin (first-index ties) over 128 via 32 lanes x 4
            {
                float mv = wu_reg0; int mi = hl;
                if (wu_reg1 < mv) { mv = wu_reg1; mi = hl + 32; }
                if (wu_reg2 < mv) { mv = wu_reg2; mi = hl + 64; }
                if (wu_reg3 < mv) { mv = wu_reg3; mi = hl + 96; }
#pragma unroll
                for (int off = 16; off; off >>= 1) {
                    float ov = __shfl_xor(mv, off);
                    int   oi = __shfl_xor(mi, off);
                    if (ov < mv || (ov == mv && oi < mi)) { mv = ov; mi = oi; }
                }
                if (hl == 0) sidx[hg] = mi;
            }
            // kth-smallest (value invariant to tie-break) + wlu
            {
                float v0 = wu_reg0, v1 = wu_reg1, v2 = wu_reg2, v3 = wu_reg3;
                float kth = 0.f;
#pragma unroll
                for (int it = 0; it < RH; ++it) {
                    float mv = v0; int mi = hl;
                    if (v1 < mv) { mv = v1; mi = hl + 32; }
                    if (v2 < mv) { mv = v2; mi = hl + 64; }
                    if (v3 < mv) { mv = v3; mi = hl + 96; }
                    for (int off = 16; off; off >>= 1) {
                        float ov = __shfl_xor(mv, off);
                        int   oi = __shfl_xor(mi, off);
                        if (ov < mv || (ov == mv && oi < mi)) { mv = ov; mi = oi; }
                    }
                    kth = mv;
                    if (mi == hl) v0 = __builtin_inff();
                    else if (mi == hl + 32) v1 = __builtin_inff();
                    else if (mi == hl + 64) v2 = __builtin_inff();
                    else v3 = (mi == hl + 96) ? __builtin_inff() : v3;
                }
                swlu[hg][hl]      = (wu_reg0 <= kth) ? 1.f : 0.f;
                swlu[hg][hl + 32] = (wu_reg1 <= kth) ? 1.f : 0.f;
                swlu[hg][hl + 64] = (wu_reg2 <= kth) ? 1.f : 0.f;
                swlu[hg][hl + 96] = (wu_reg3 <= kth) ? 1.f : 0.f;
            }
        }
        __syncthreads();

        // ==== B: LSTM cell (400 thr); c in regs; prefetch next gx ====
        if (tid < NG * HDIM) {
            float ig = sigmoidf_(sgate[pg][pj] + gxr0);
            float fg = sigmoidf_(sgate[pg][pj + HDIM] + gxr1);
            float gv = ftanh(sgate[pg][pj + 2 * HDIM] + gxr2);
            float og = sigmoidf_(sgate[pg][pj + 3 * HDIM] + gxr3);
            c_reg = fg * c_reg + ig * gv;
            float h = og * ftanh(c_reg);
            sh[pg][pj] = h;
            shh[pg][pj] = (_Float16)h;
            if (t + 1 < TSTEPS) {
                const float* gxp = gx + ((size_t)(t + 1) * BATCH + b0 + pg) * G4H + pj;
                gxr0 = gxp[0]; gxr1 = gxp[HDIM]; gxr2 = gxp[2 * HDIM]; gxr3 = gxp[3 * HDIM];
            }
        }
        __syncthreads();

        // ==== C: keys full-K via fdot2 (320 thr) | sigma via shfl (32 thr) ====
        if (tid < 320) {
            int g = tid / 160, col = tid - (tid / 160) * 160;
            const uint2* wq = Wk_q2 + col;
            float a = 0.f;
#pragma unroll 5
            for (int q = 0; q < 50; ++q) {
                uint2 wv = wq[q * RD];
                uint2 hp = *(const uint2*)&shh[g][q * 4];
                a = fdot2_(wv.x, hp.x, a);
                a = fdot2_(wv.y, hp.y, a);
            }
            sk[g][col / DMEM][col % DMEM] = ftanh(a + bk[col]);
        } else if (tid < 352) {
            int v = tid - 320; int g = v >> 4, rc = v & 15, r = rc >> 2, cc = rc & 3;
            const float* wrow = Wsm + r * HDIM;
            float a = 0.f;
            for (int j = 50 * cc; j < 50 * cc + 50; ++j) a += sh[g][j] * wrow[j];
            a += __shfl_xor(a, 1);
            a += __shfl_xor(a, 2);
            if (cc == 0) ssig[g][r] = sigmoidf_(ftanh(a + bs[r]));
        }
        __syncthreads();

        // ==== E2'+NF fused: ww, zero-LU-row, M update, cosine dots, norms ====
        if (tid < 256) {
            int g = tid >> 7, m = tid & 127;
            float sg0 = ssig[g][0], sg1 = ssig[g][1], sg2 = ssig[g][2], sg3 = ssig[g][3];
            float wl = swlu[g][m];
            float w0 = sg0 * swr[g][0][m] + (1.f - sg0) * wl;
            float w1 = sg1 * swr[g][1][m] + (1.f - sg1) * wl;
            float w2 = sg2 * swr[g][2][m] + (1.f - sg2) * wl;
            float w3 = sg3 * swr[g][3][m] + (1.f - sg3) * wl;
            sww[g][0][m] = w0; sww[g][1][m] = w1;
            sww[g][2][m] = w2; sww[g][3][m] = w3;
            bool zr = (m == sidx[g]);
            float d0 = 0.f, d1 = 0.f, d2 = 0.f, d3 = 0.f, nn = 0.f;
#pragma unroll
            for (int q = 0; q < 10; ++q) {
                int d = q * 4;
                float4 mv = *(const float4*)&sM[g][m][d];
                float4 k0 = *(const float4*)&sk[g][0][d];
                float4 k1 = *(const float4*)&sk[g][1][d];
                float4 k2 = *(const float4*)&sk[g][2][d];
                float4 k3 = *(const float4*)&sk[g][3][d];
                float4 o;
                o.x = (zr ? 0.f : mv.x) + w0 * k0.x + w1 * k1.x + w2 * k2.x + w3 * k3.x;
                o.y = (zr ? 0.f : mv.y) + w0 * k0.y + w1 * k1.y + w2 * k2.y + w3 * k3.y;
                o.z = (zr ? 0.f : mv.z) + w0 * k0.z + w1 * k1.z + w2 * k2.z + w3 * k3.z;
                o.w = (zr ? 0.f : mv.w) + w0 * k0.w + w1 * k1.w + w2 * k2.w + w3 * k3.w;
                *(float4*)&sM[g][m][d] = o;
                d0 += k0.x * o.x + k0.y * o.y + k0.z * o.z + k0.w * o.w;
                d1 += k1.x * o.x + k1.y * o.y + k1.z * o.z + k1.w * o.w;
                d2 += k2.x * o.x + k2.y * o.y + k2.z * o.z + k2.w * o.w;
                d3 += k3.x * o.x + k3.y * o.y + k3.z * o.z + k3.w * o.w;
                nn += o.x * o.x + o.y * o.y + o.z * o.z + o.w * o.w;
            }
            sKs[g][0][m] = d0; sKs[g][1][m] = d1;
            sKs[g][2][m] = d2; sKs[g][3][m] = d3;
            snM[g][m] = sqrtf(nn);
        } else if (tid < 264) {
            int v = tid - 256; int g2 = v >> 2, r2 = v & 3;
            float a0 = 0.f, a1 = 0.f, a2 = 0.f, a3 = 0.f;
#pragma unroll
            for (int q = 0; q < 10; ++q) {
                float4 kv = *(const float4*)&sk[g2][r2][q * 4];
                a0 += kv.x * kv.x; a1 += kv.y * kv.y;
                a2 += kv.z * kv.z; a3 += kv.w * kv.w;
            }
            snk[g2][r2] = sqrtf((a0 + a1) + (a2 + a3));
        }
        __syncthreads();

        // ==== G+H fused: softmax -> swr -> same-wave read-vector slice ====
        {
            int g = w >> 2, r = w & 3;
            float ink = snk[g][r];
            float a = sKs[g][r][l] / (ink * snM[g][l]);
            float b = sKs[g][r][l + 64] / (ink * snM[g][l + 64]);
            float mx = fmaxf(a, b);
#pragma unroll
            for (int off = 32; off; off >>= 1) mx = fmaxf(mx, __shfl_xor(mx, off));
            float ea = __expf(a - mx), eb = __expf(b - mx);
            float s = ea + eb;
#pragma unroll
            for (int off = 32; off; off >>= 1) s += __shfl_xor(s, off);
            float inv = 1.f / s;
            swr[g][r][l]      = ea * inv;
            swr[g][r][l + 64] = eb * inv;
            // read vector slice for this (g,r): 10 d4-slots x 2 m-halves
            int d4 = l & 31;
            if (d4 < 10) {
                int mb = (l >> 5) * 64;
                float a0 = 0.f, a1 = 0.f, a2 = 0.f, a3 = 0.f;
                for (int m = mb; m < mb + 64; ++m) {
                    float wv = swr[g][r][m];
                    float4 mv = *(const float4*)&sM[g][m][d4 * 4];
                    a0 += wv * mv.x; a1 += wv * mv.y;
                    a2 += wv * mv.z; a3 += wv * mv.w;
                }
                a0 += __shfl_xor(a0, 32);
                a1 += __shfl_xor(a1, 32);
                a2 += __shfl_xor(a2, 32);
                a3 += __shfl_xor(a3, 32);
                if (l < 10) {
                    float4 res = {a0, a1, a2, a3};
                    *(float4*)&sr[g][r * DMEM + d4 * 4] = res;
                }
            }
        }
        __syncthreads();
    }

    // ---- epilogue: head for the final step (both halves of wave 7) ----
    if (w == 7) head_half(l >> 5, TSTEPS - 1);
}

extern "C" void kernel_launch(void* const* d_in, const int* in_sizes, int n_in,
                              void* d_out, int out_size, void* d_ws, size_t ws_size,
                              hipStream_t stream) {
    const float* x    = (const float*)d_in[0];
    const float* W_ih = (const float*)d_in[1];
    const float* W_hh = (const float*)d_in[2];
    const float* b_ih = (const float*)d_in[3];
    const float* b_hh = (const float*)d_in[4];
    const float* Wk   = (const float*)d_in[5];
    const float* bk   = (const float*)d_in[6];
    const float* Wsm  = (const float*)d_in[7];
    const float* bs   = (const float*)d_in[8];
    const float* Wo   = (const float*)d_in[9];
    const float* bo   = (const float*)d_in[10];
    float* out = (float*)d_out;

    const size_t gx_elems  = (size_t)TSTEPS * BATCH * G4H;  // 40,960,000 f32
    const size_t whh_q4_e  = (size_t)50 * 400;              // uint4 (16B)
    const size_t wk_q2_e   = (size_t)50 * 160;              // uint2 (8B)
    const size_t a_elems   = (size_t)TSTEPS * BATCH * KP;   // u16 each
    const size_t w_elems   = (size_t)2 * WROWS * KP;        // u16
    const size_t need_base = gx_elems * 4 + whh_q4_e * 16 + wk_q2_e * 8;
    const size_t need_mfma = need_base + (2 * a_elems + w_elems) * 2;
    if (ws_size < need_base) return;

    float* gxb = (float*)d_ws;
    uint4* Whh_q4 = (uint4*)(gxb + gx_elems);
    uint2* Wk_q2  = (uint2*)(Whh_q4 + whh_q4_e);

    {
        int tot = (int)(whh_q4_e + wk_q2_e);
        convert_recQ<<<dim3((tot + 255) / 256), dim3(256), 0, stream>>>(W_hh, Wk, Whh_q4, Wk_q2);
    }

    if (ws_size >= need_mfma) {
        unsigned short* Ahi = (unsigned short*)(Wk_q2 + wk_q2_e);
        unsigned short* Alo = Ahi + a_elems;
        unsigned short* Wpk = Alo + a_elems;
        convert_A<<<dim3(2, TSTEPS * BATCH), dim3(256), 0, stream>>>(x, Ahi, Alo);
        convert_W<<<dim3(2, WROWS, 2), dim3(256), 0, stream>>>(W_ih, Wpk);
        gx_gemm_mfma<<<dim3(7, (TSTEPS * BATCH) / 128), dim3(256), 0, stream>>>(
            Ahi, Alo, Wpk, b_ih, b_hh, gxb);
    } else {
        gx_gemm<<<dim3(G4H / 80, (TSTEPS * BATCH) / 128), dim3(256), 0, stream>>>(
            x, W_ih, b_ih, b_hh, gxb);
    }

    ntm_scan<<<dim3(BATCH / NG), dim3(512), 0, stream>>>(
        gxb, Whh_q4, Wk_q2, bk, Wsm, bs, Wo, bo, out);
}

// Round 14
// 1321.719 us; speedup vs baseline: 1.3636x; 1.0286x over previous
//
#include <hip/hip_runtime.h>
#include <stdint.h>

#define TSTEPS 50
#define BATCH  1024
#define INDIM  405
#define KP     448      // padded K for gx GEMM (7 x 64)
#define HDIM   200
#define G4H    800      // 4*H
#define NMEM   128
#define DMEM   40
#define DPAD   44       // sM row stride: 16B-aligned
#define RH     4
#define RD     160      // RH*DMEM
#define NWAY   5
#define GAMMA_ 0.99f
#define NG     2        // batches per block; 512 blocks, 512 thr -> 2 blocks/CU
#define WROWS  928      // gx GEMM W rows padded

typedef __attribute__((ext_vector_type(8))) short short8;
typedef __attribute__((ext_vector_type(4))) float f32x4;
typedef _Float16 h2 __attribute__((ext_vector_type(2)));

__device__ __forceinline__ float sigmoidf_(float x) {
    return 1.f / (1.f + __expf(-x));
}
__device__ __forceinline__ float ftanh(float x) {
    float e = __expf(2.f * x);
    return 1.f - 2.f / (e + 1.f);
}
__device__ __forceinline__ unsigned short f2bf(float f) {   // RNE f32->bf16
    uint32_t u = __float_as_uint(f);
    uint32_t r = u + 0x7FFFu + ((u >> 16) & 1u);
    return (unsigned short)(r >> 16);
}
__device__ __forceinline__ float bf2f(unsigned short h) {
    return __uint_as_float(((uint32_t)h) << 16);
}
__device__ __forceinline__ h2 u2h(uint32_t u) {
    union { uint32_t u; h2 h; } c; c.u = u; return c.h;
}
__device__ __forceinline__ float fdot2_(uint32_t w, uint32_t h, float acc) {
#if __has_builtin(__builtin_amdgcn_fdot2)
    return __builtin_amdgcn_fdot2(u2h(w), u2h(h), acc, false);
#else
    union { uint32_t u; _Float16 f[2]; } cw, ch;
    cw.u = w; ch.u = h;
    return acc + (float)cw.f[0] * (float)ch.f[0] + (float)cw.f[1] * (float)ch.f[1];
#endif
}
__device__ __forceinline__ uint32_t pkh(float a, float b) {  // pack 2 f32 -> f16x2
    union { _Float16 f[2]; uint32_t u; } c;
    c.f[0] = (_Float16)a; c.f[1] = (_Float16)b; return c.u;
}

// ---- pack recurrent weights as f16 pairs (A quad / Wk pair / Wsm pair) -----
__global__ __launch_bounds__(256) void convert_recQ(const float* __restrict__ W_hh,
                                                    const float* __restrict__ Wk,
                                                    const float* __restrict__ Wsm,
                                                    uint4* __restrict__ Whh_q4,
                                                    uint2* __restrict__ Wk_q2,
                                                    uint32_t* __restrict__ Wsm_q) {
    int i = blockIdx.x * 256 + threadIdx.x;
    if (i < 50 * 400) {
        int jq = i / 400, p = i % 400;
        int j = jq * 4;
        const float* r0 = W_hh + (2 * p) * HDIM;
        const float* r1 = W_hh + (2 * p + 1) * HDIM;
        uint4 v;
        v.x = pkh(r0[j],     r0[j + 1]);
        v.y = pkh(r1[j],     r1[j + 1]);
        v.z = pkh(r0[j + 2], r0[j + 3]);
        v.w = pkh(r1[j + 2], r1[j + 3]);
        Whh_q4[i] = v;
    } else if (i < 50 * 400 + 50 * 160) {
        int e = i - 50 * 400;
        int jq = e / 160, col = e % 160;
        int j = jq * 4;
        const float* r = Wk + col * HDIM;
        uint2 v;
        v.x = pkh(r[j],     r[j + 1]);
        v.y = pkh(r[j + 2], r[j + 3]);
        Wk_q2[e] = v;
    } else if (i < 50 * 400 + 50 * 160 + 400) {
        int e = i - (50 * 400 + 50 * 160);
        int r = e / 100, jp = e % 100;
        Wsm_q[e] = pkh(Wsm[r * HDIM + 2 * jp], Wsm[r * HDIM + 2 * jp + 1]);
    }
}

// ---------------- split f32 -> (hi, lo) bf16, zero-padded K (gx GEMM) ------
__global__ __launch_bounds__(256) void convert_A(const float* __restrict__ x,
                                                 unsigned short* __restrict__ Ahi,
                                                 unsigned short* __restrict__ Alo) {
    int c = blockIdx.x * 256 + threadIdx.x;
    int r = blockIdx.y;
    if (c >= KP) return;
    float v = (c < INDIM) ? x[(size_t)r * INDIM + c] : 0.f;
    unsigned short hi = f2bf(v);
    unsigned short lo = f2bf(v - bf2f(hi));
    size_t o = (size_t)r * KP + c;
    Ahi[o] = hi;
    Alo[o] = lo;
}

__global__ __launch_bounds__(256) void convert_W(const float* __restrict__ W_ih,
                                                 unsigned short* __restrict__ Wpk) {
    int c = blockIdx.x * 256 + threadIdx.x;
    int n = blockIdx.y;
    int sec = blockIdx.z;
    if (c >= KP) return;
    float v = (n < G4H && c < INDIM) ? W_ih[(size_t)n * INDIM + c] : 0.f;
    unsigned short hi = f2bf(v);
    size_t o = (size_t)sec * WROWS * KP + (size_t)n * KP + c;
    Wpk[o] = (sec == 0) ? hi : f2bf(v - bf2f(hi));
}

// ---------------- gx GEMM via 3-term split-bf16 MFMA ----------------------
__global__ __launch_bounds__(256) void gx_gemm_mfma(
        const unsigned short* __restrict__ Ahi,
        const unsigned short* __restrict__ Alo,
        const unsigned short* __restrict__ Wpk,
        const float* __restrict__ b_ih, const float* __restrict__ b_hh,
        float* __restrict__ gx) {
    __shared__ unsigned short Alds[128 * 64];
    __shared__ unsigned short Blds[128 * 64];
    const int tid = threadIdx.x;
    const int wv = tid >> 6, ln = tid & 63;
    const int wr = wv >> 1, wc = wv & 1;
    const int n0 = blockIdx.x * 128;
    const int m0 = blockIdx.y * 128;

    f32x4 acc[4][4];
#pragma unroll
    for (int m = 0; m < 4; ++m)
#pragma unroll
        for (int n = 0; n < 4; ++n) acc[m][n] = (f32x4){0.f, 0.f, 0.f, 0.f};

    int erow[4], ecol[4];
#pragma unroll
    for (int i = 0; i < 4; ++i) {
        int e = (i * 4 + wv) * 512 + ln * 8;
        erow[i] = e >> 6;
        ecol[i] = e & 63;
    }

    const unsigned short* Whi = Wpk;
    const unsigned short* Wlo = Wpk + (size_t)WROWS * KP;

#pragma unroll 1
    for (int s = 0; s < 3; ++s) {
        const unsigned short* Ab = ((s == 2) ? Alo : Ahi) + (size_t)m0 * KP;
        const unsigned short* Bb = ((s == 1) ? Wlo : Whi) + (size_t)n0 * KP;

        short8 ar[4], br[4];
#pragma unroll
        for (int i = 0; i < 4; ++i) {
            ar[i] = *(const short8*)&Ab[(size_t)erow[i] * KP + ecol[i]];
            br[i] = *(const short8*)&Bb[(size_t)erow[i] * KP + ecol[i]];
        }

#pragma unroll 1
        for (int k0 = 0; k0 < KP; k0 += 64) {
            __syncthreads();
#pragma unroll
            for (int i = 0; i < 4; ++i) {
                int e = (i * 4 + wv) * 512 + ln * 8;
                *(short8*)&Alds[e] = ar[i];
                *(short8*)&Blds[e] = br[i];
            }
            __syncthreads();
            if (k0 + 64 < KP) {
#pragma unroll
                for (int i = 0; i < 4; ++i) {
                    ar[i] = *(const short8*)&Ab[(size_t)erow[i] * KP + k0 + 64 + ecol[i]];
                    br[i] = *(const short8*)&Bb[(size_t)erow[i] * KP + k0 + 64 + ecol[i]];
                }
            }
#pragma unroll
            for (int ks = 0; ks < 2; ++ks) {
                short8 af[4], bf[4];
                int kcol = ks * 32 + (ln >> 4) * 8;
#pragma unroll
                for (int m = 0; m < 4; ++m) {
                    int row = wr * 64 + m * 16 + (ln & 15);
                    af[m] = *(const short8*)&Alds[row * 64 + kcol];
                }
#pragma unroll
                for (int n = 0; n < 4; ++n) {
                    int row = wc * 64 + n * 16 + (ln & 15);
                    bf[n] = *(const short8*)&Blds[row * 64 + kcol];
                }
#pragma unroll
                for (int m = 0; m < 4; ++m)
#pragma unroll
                    for (int n = 0; n < 4; ++n)
                        acc[m][n] = __builtin_amdgcn_mfma_f32_16x16x32_bf16(
                            af[m], bf[n], acc[m][n], 0, 0, 0);
            }
        }
    }

#pragma unroll
    for (int n = 0; n < 4; ++n) {
        int col = n0 + wc * 64 + n * 16 + (ln & 15);
        if (col >= G4H) continue;
        float bias = b_ih[col] + b_hh[col];
#pragma unroll
        for (int m = 0; m < 4; ++m) {
#pragma unroll
            for (int j = 0; j < 4; ++j) {
                int row = m0 + wr * 64 + m * 16 + (ln >> 4) * 4 + j;
                gx[(size_t)row * G4H + col] = acc[m][n][j] + bias;
            }
        }
    }
}

// ---------------- f32 fallback GEMM ---------------------------------------
__global__ __launch_bounds__(256) void gx_gemm(const float* __restrict__ x,
                                               const float* __restrict__ W_ih,
                                               const float* __restrict__ b_ih,
                                               const float* __restrict__ b_hh,
                                               float* __restrict__ gx) {
    const int BM = 128, BN = 80, BK = 16;
    __shared__ float As[BK][BM];
    __shared__ float Bs[BK][BN];
    int m0 = blockIdx.y * BM;
    int n0 = blockIdx.x * BN;
    int tid = threadIdx.x;
    int tm = tid >> 4, tn = tid & 15;
    float acc[8][5];
#pragma unroll
    for (int i = 0; i < 8; ++i)
#pragma unroll
        for (int j = 0; j < 5; ++j) acc[i][j] = 0.f;

    for (int k0 = 0; k0 < INDIM; k0 += BK) {
        {
            int row = tid >> 1, kk = (tid & 1) * 8;
            const float* ap = x + (size_t)(m0 + row) * INDIM + k0 + kk;
#pragma unroll
            for (int i = 0; i < 8; ++i)
                As[kk + i][row] = (k0 + kk + i < INDIM) ? ap[i] : 0.f;
        }
        if (tid < 160) {
            int col = tid >> 1, kk = (tid & 1) * 8;
            const float* bp = W_ih + (size_t)(n0 + col) * INDIM + k0 + kk;
#pragma unroll
            for (int i = 0; i < 8; ++i)
                Bs[kk + i][col] = (k0 + kk + i < INDIM) ? bp[i] : 0.f;
        }
        __syncthreads();
#pragma unroll
        for (int k = 0; k < BK; ++k) {
            float a[8], b[5];
#pragma unroll
            for (int i = 0; i < 8; ++i) a[i] = As[k][tm * 8 + i];
#pragma unroll
            for (int j = 0; j < 5; ++j) b[j] = Bs[k][tn * 5 + j];
#pragma unroll
            for (int i = 0; i < 8; ++i)
#pragma unroll
                for (int j = 0; j < 5; ++j) acc[i][j] += a[i] * b[j];
        }
        __syncthreads();
    }
#pragma unroll
    for (int j = 0; j < 5; ++j) {
        int n = n0 + tn * 5 + j;
        float bias = b_ih[n] + b_hh[n];
#pragma unroll
        for (int i = 0; i < 8; ++i) {
            int m = m0 + tm * 8 + i;
            gx[(size_t)m * G4H + n] = acc[i][j] + bias;
        }
    }
}

// ---------------- persistent NTM scan: NG=2, 512 thr, 5 barriers/step ------
__global__ __launch_bounds__(512, 4) void ntm_scan(
        const float* __restrict__ gx,          // [T][B][800]
        const uint4* __restrict__ Whh_q4,      // [50][400] quad-packed f16
        const uint2* __restrict__ Wk_q2,       // [50][160] pair-packed f16
        const float* __restrict__ bk,
        const uint32_t* __restrict__ Wsm_q,    // [4][100] pair-packed f16
        const float* __restrict__ bs,
        const float* __restrict__ Wo,          // [5][360]
        const float* __restrict__ bo,
        float* __restrict__ out) {             // [T][B][5]
    __shared__ float sM[NG][NMEM][DPAD];
    __shared__ float sh[NG][HDIM];
    __shared__ _Float16 shh[NG][HDIM];         // f16 mirror of h
    __shared__ float sgate[NG][G4H];
    __shared__ float swr[NG][RH][NMEM];
    __shared__ float sww[NG][RH][NMEM];
    __shared__ float sKsP[2][NG][RH][NMEM];    // cosine-dot partials (d-halves)
    __shared__ float snnP[2][NG][NMEM];        // row-norm^2 partials
    __shared__ float swlu[NG][NMEM];
    __shared__ float sk[NG][RH][DMEM];
    __shared__ float sr[NG][RD];
    __shared__ float snk[NG][RH];
    __shared__ float ssig[NG][RH];
    __shared__ int   sidx[NG];

    const int tid = threadIdx.x;
    const int b0  = blockIdx.x * NG;
    const int w   = tid >> 6, l = tid & 63;

    // ---- init carries ----
    for (int e = tid; e < NG * NMEM * DPAD; e += 512) ((float*)sM)[e] = 0.f;
    for (int e = tid; e < NG * HDIM; e += 512) { ((float*)sh)[e] = 0.f; ((_Float16*)shh)[e] = (_Float16)0.f; }
    for (int e = tid; e < NG * RH * NMEM; e += 512) ((float*)swr)[e] = 0.f;
    for (int e = tid; e < NG * NMEM; e += 512) ((float*)swlu)[e] = 1.f;

    float c_reg = 0.f;
    float gxr0 = 0.f, gxr1 = 0.f, gxr2 = 0.f, gxr3 = 0.f;
    int pg = 0, pj = 0;
    if (tid < NG * HDIM) {
        pg = tid / HDIM; pj = tid - pg * HDIM;
        const float* gxp = gx + (size_t)(b0 + pg) * G4H + pj;
        gxr0 = gxp[0]; gxr1 = gxp[HDIM]; gxr2 = gxp[2 * HDIM]; gxr3 = gxp[3 * HDIM];
    }
    // wave-7 register-resident usage: lane (hg=l>>5, hl=l&31) owns wu[g=hg][hl+32k]
    float wu_reg0 = 0.f, wu_reg1 = 0.f, wu_reg2 = 0.f, wu_reg3 = 0.f;
    __syncthreads();

    // half-wave (32-lane) output head for group g, step tt; reads sh, sr
    auto head_half = [&](int g, int tt) {
        const int hl = l & 31;
        float v[NWAY];
#pragma unroll
        for (int o = 0; o < NWAY; ++o) {
            const float* wrow = Wo + o * (HDIM + RD);
            float acc = 0.f;
            for (int j = hl; j < HDIM; j += 32) acc += sh[g][j] * wrow[j];
            for (int d = hl; d < RD; d += 32) acc += sr[g][d] * wrow[HDIM + d];
#pragma unroll
            for (int off = 16; off; off >>= 1) acc += __shfl_xor(acc, off);
            v[o] = acc + bo[o];
        }
        if (hl == 0) {
            float mx = -1e30f;
#pragma unroll
            for (int o = 0; o < NWAY; ++o) { v[o] = sigmoidf_(v[o]); mx = fmaxf(mx, v[o]); }
            float s = 0.f;
#pragma unroll
            for (int o = 0; o < NWAY; ++o) { v[o] = __expf(v[o] - mx); s += v[o]; }
            float inv = 1.f / s;
            float* op = out + ((size_t)tt * BATCH + (b0 + g)) * NWAY;
#pragma unroll
            for (int o = 0; o < NWAY; ++o) op[o] = v[o] * inv;
        }
    };

    for (int t = 0; t < TSTEPS; ++t) {
        // ==== A: gates GEMV via fdot2 (thr 0-399) | wave 7 aux ====
        if (tid < 400) {
            const uint4* wq = Whh_q4 + tid;
            float a00 = 0.f, a01 = 0.f, a10 = 0.f, a11 = 0.f;
#pragma unroll 5
            for (int jq = 0; jq < 50; ++jq) {
                uint4 wv = wq[jq * 400];
                uint2 hp0 = *(const uint2*)&shh[0][jq * 4];
                uint2 hp1 = *(const uint2*)&shh[1][jq * 4];
                a00 = fdot2_(wv.x, hp0.x, a00);
                a00 = fdot2_(wv.z, hp0.y, a00);
                a01 = fdot2_(wv.y, hp0.x, a01);
                a01 = fdot2_(wv.w, hp0.y, a01);
                a10 = fdot2_(wv.x, hp1.x, a10);
                a10 = fdot2_(wv.z, hp1.y, a10);
                a11 = fdot2_(wv.y, hp1.x, a11);
                a11 = fdot2_(wv.w, hp1.y, a11);
            }
            sgate[0][2 * tid]     = a00;
            sgate[0][2 * tid + 1] = a01;
            sgate[1][2 * tid]     = a10;
            sgate[1][2 * tid + 1] = a11;
        } else if (w == 7) {
            const int hg = l >> 5;     // lanes 0-31 -> g0, 32-63 -> g1
            const int hl = l & 31;
            if (t > 0) {
                head_half(hg, t - 1);
                // usage update in registers (same per-r order as before)
#pragma unroll
                for (int k = 0; k < 4; ++k) {
                    int m = hl + 32 * k;
                    float wu = GAMMA_ * ((k == 0) ? wu_reg0 : (k == 1) ? wu_reg1
                                         : (k == 2) ? wu_reg2 : wu_reg3);
#pragma unroll
                    for (int r = 0; r < RH; ++r) wu += swr[hg][r][m] + sww[hg][r][m];
                    if (k == 0) wu_reg0 = wu; else if (k == 1) wu_reg1 = wu;
                    else if (k == 2) wu_reg2 = wu; else wu_reg3 = wu;
                }
            }
            // argmin (first-index ties) over 128 via 32 lanes x 4
            {
                float mv = wu_reg0; int mi = hl;
                if (wu_reg1 < mv) { mv = wu_reg1; mi = hl + 32; }
                if (wu_reg2 < mv) { mv = wu_reg2; mi = hl + 64; }
                if (wu_reg3 < mv) { mv = wu_reg3; mi = hl + 96; }
#pragma unroll
                for (int off = 16; off; off >>= 1) {
                    float ov = __shfl_xor(mv, off);
                    int   oi = __shfl_xor(mi, off);
                    if (ov < mv || (ov == mv && oi < mi)) { mv = ov; mi = oi; }
                }
                if (hl == 0) sidx[hg] = mi;
            }
            // kth-smallest (value invariant to tie-break) + wlu
            {
                float v0 = wu_reg0, v1 = wu_reg1, v2 = wu_reg2, v3 = wu_reg3;
                float kth = 0.f;
#pragma unroll
                for (int it = 0; it < RH; ++it) {
                    float mv = v0; int mi = hl;
                    if (v1 < mv) { mv = v1; mi = hl + 32; }
                    if (v2 < mv) { mv = v2; mi = hl + 64; }
                    if (v3 < mv) { mv = v3; mi = hl + 96; }
                    for (int off = 16; off; off >>= 1) {
                        float ov = __shfl_xor(mv, off);
                        int   oi = __shfl_xor(mi, off);
                        if (ov < mv || (ov == mv && oi < mi)) { mv = ov; mi = oi; }
                    }
                    kth = mv;
                    if (mi == hl) v0 = __builtin_inff();
                    else if (mi == hl + 32) v1 = __builtin_inff();
                    else if (mi == hl + 64) v2 = __builtin_inff();
                    else v3 = (mi == hl + 96) ? __builtin_inff() : v3;
                }
                swlu[hg][hl]      = (wu_reg0 <= kth) ? 1.f : 0.f;
                swlu[hg][hl + 32] = (wu_reg1 <= kth) ? 1.f : 0.f;
                swlu[hg][hl + 64] = (wu_reg2 <= kth) ? 1.f : 0.f;
                swlu[hg][hl + 96] = (wu_reg3 <= kth) ? 1.f : 0.f;
            }
        }
        __syncthreads();

        // ==== B: LSTM cell (400 thr); c in regs; prefetch next gx ====
        if (tid < NG * HDIM) {
            float ig = sigmoidf_(sgate[pg][pj] + gxr0);
            float fg = sigmoidf_(sgate[pg][pj + HDIM] + gxr1);
            float gv = ftanh(sgate[pg][pj + 2 * HDIM] + gxr2);
            float og = sigmoidf_(sgate[pg][pj + 3 * HDIM] + gxr3);
            c_reg = fg * c_reg + ig * gv;
            float h = og * ftanh(c_reg);
            sh[pg][pj] = h;
            shh[pg][pj] = (_Float16)h;
            if (t + 1 < TSTEPS) {
                const float* gxp = gx + ((size_t)(t + 1) * BATCH + b0 + pg) * G4H + pj;
                gxr0 = gxp[0]; gxr1 = gxp[HDIM]; gxr2 = gxp[2 * HDIM]; gxr3 = gxp[3 * HDIM];
            }
        }
        __syncthreads();

        // ==== C: keys full-K via fdot2 (320 thr) | sigma via fdot2 (32 thr) ====
        if (tid < 320) {
            int g = tid / 160, col = tid - (tid / 160) * 160;
            const uint2* wq = Wk_q2 + col;
            float a = 0.f;
#pragma unroll 5
            for (int q = 0; q < 50; ++q) {
                uint2 wv = wq[q * RD];
                uint2 hp = *(const uint2*)&shh[g][q * 4];
                a = fdot2_(wv.x, hp.x, a);
                a = fdot2_(wv.y, hp.y, a);
            }
            sk[g][col / DMEM][col % DMEM] = ftanh(a + bk[col]);
        } else if (tid < 352) {
            int v = tid - 320; int g = v >> 4, rc = v & 15, r = rc >> 2, cc = rc & 3;
            const uint32_t* wq = Wsm_q + r * 100 + cc * 25;
            const uint32_t* hp = (const uint32_t*)&shh[g][cc * 50];
            float a = 0.f;
#pragma unroll 5
            for (int q = 0; q < 25; ++q) a = fdot2_(wq[q], hp[q], a);
            a += __shfl_xor(a, 1);
            a += __shfl_xor(a, 2);
            if (cc == 0) ssig[g][r] = sigmoidf_(ftanh(a + bs[r]));
        }
        __syncthreads();

        // ==== E2'+NF fused, split over ALL 512 thr: (g,m) x d-half ====
        {
            int t2 = tid & 255;
            int g = t2 >> 7, m = t2 & 127, dh = tid >> 8;   // wave-uniform dh
            float sg0 = ssig[g][0], sg1 = ssig[g][1], sg2 = ssig[g][2], sg3 = ssig[g][3];
            float wl = swlu[g][m];
            float w0 = sg0 * swr[g][0][m] + (1.f - sg0) * wl;
            float w1 = sg1 * swr[g][1][m] + (1.f - sg1) * wl;
            float w2 = sg2 * swr[g][2][m] + (1.f - sg2) * wl;
            float w3 = sg3 * swr[g][3][m] + (1.f - sg3) * wl;
            if (dh == 0) {
                sww[g][0][m] = w0; sww[g][1][m] = w1;
                sww[g][2][m] = w2; sww[g][3][m] = w3;
            }
            bool zr = (m == sidx[g]);
            float d0 = 0.f, d1 = 0.f, d2 = 0.f, d3 = 0.f, nn = 0.f;
            int q0 = dh * 5;
#pragma unroll
            for (int q = 0; q < 5; ++q) {
                int d = (q0 + q) * 4;
                float4 mv = *(const float4*)&sM[g][m][d];
                float4 k0 = *(const float4*)&sk[g][0][d];
                float4 k1 = *(const float4*)&sk[g][1][d];
                float4 k2 = *(const float4*)&sk[g][2][d];
                float4 k3 = *(const float4*)&sk[g][3][d];
                float4 o;
                o.x = (zr ? 0.f : mv.x) + w0 * k0.x + w1 * k1.x + w2 * k2.x + w3 * k3.x;
                o.y = (zr ? 0.f : mv.y) + w0 * k0.y + w1 * k1.y + w2 * k2.y + w3 * k3.y;
                o.z = (zr ? 0.f : mv.z) + w0 * k0.z + w1 * k1.z + w2 * k2.z + w3 * k3.z;
                o.w = (zr ? 0.f : mv.w) + w0 * k0.w + w1 * k1.w + w2 * k2.w + w3 * k3.w;
                *(float4*)&sM[g][m][d] = o;
                d0 += k0.x * o.x + k0.y * o.y + k0.z * o.z + k0.w * o.w;
                d1 += k1.x * o.x + k1.y * o.y + k1.z * o.z + k1.w * o.w;
                d2 += k2.x * o.x + k2.y * o.y + k2.z * o.z + k2.w * o.w;
                d3 += k3.x * o.x + k3.y * o.y + k3.z * o.z + k3.w * o.w;
                nn += o.x * o.x + o.y * o.y + o.z * o.z + o.w * o.w;
            }
            sKsP[dh][g][0][m] = d0; sKsP[dh][g][1][m] = d1;
            sKsP[dh][g][2][m] = d2; sKsP[dh][g][3][m] = d3;
            snnP[dh][g][m] = nn;
            if (tid < 8) {   // ||k|| (small extra on wave 0)
                int g2 = tid >> 2, r2 = tid & 3;
                float a0 = 0.f, a1 = 0.f, a2 = 0.f, a3 = 0.f;
#pragma unroll
                for (int q = 0; q < 10; ++q) {
                    float4 kv = *(const float4*)&sk[g2][r2][q * 4];
                    a0 += kv.x * kv.x; a1 += kv.y * kv.y;
                    a2 += kv.z * kv.z; a3 += kv.w * kv.w;
                }
                snk[g2][r2] = sqrtf((a0 + a1) + (a2 + a3));
            }
        }
        __syncthreads();

        // ==== G+H fused: combine partials, softmax, read-vector (all lanes) ====
        {
            int g = w >> 2, r = w & 3;
            float ink = snk[g][r];
            float n0 = snnP[0][g][l] + snnP[1][g][l];
            float n1 = snnP[0][g][l + 64] + snnP[1][g][l + 64];
            float a = (sKsP[0][g][r][l] + sKsP[1][g][r][l]) / (ink * sqrtf(n0));
            float b = (sKsP[0][g][r][l + 64] + sKsP[1][g][r][l + 64]) / (ink * sqrtf(n1));
            float mx = fmaxf(a, b);
#pragma unroll
            for (int off = 32; off; off >>= 1) mx = fmaxf(mx, __shfl_xor(mx, off));
            float ea = __expf(a - mx), eb = __expf(b - mx);
            float s = ea + eb;
#pragma unroll
            for (int off = 32; off; off >>= 1) s += __shfl_xor(s, off);
            float inv = 1.f / s;
            swr[g][r][l]      = ea * inv;
            swr[g][r][l + 64] = eb * inv;
            // read vector: lane = (m-quarter = l>>4, d4 = l&15); 32 m-iters
            int d4 = l & 15;
            int mb = (l >> 4) * 32;
            float a0 = 0.f, a1 = 0.f, a2 = 0.f, a3 = 0.f;
            if (d4 < 10) {
                for (int m = mb; m < mb + 32; ++m) {
                    float wv = swr[g][r][m];
                    float4 mv = *(const float4*)&sM[g][m][d4 * 4];
                    a0 += wv * mv.x; a1 += wv * mv.y;
                    a2 += wv * mv.z; a3 += wv * mv.w;
                }
            }
            a0 += __shfl_xor(a0, 16); a0 += __shfl_xor(a0, 32);
            a1 += __shfl_xor(a1, 16); a1 += __shfl_xor(a1, 32);
            a2 += __shfl_xor(a2, 16); a2 += __shfl_xor(a2, 32);
            a3 += __shfl_xor(a3, 16); a3 += __shfl_xor(a3, 32);
            if (l < 10) {
                float4 res = {a0, a1, a2, a3};
                *(float4*)&sr[g][r * DMEM + l * 4] = res;
            }
        }
        __syncthreads();
    }

    // ---- epilogue: head for the final step (both halves of wave 7) ----
    if (w == 7) head_half(l >> 5, TSTEPS - 1);
}

extern "C" void kernel_launch(void* const* d_in, const int* in_sizes, int n_in,
                              void* d_out, int out_size, void* d_ws, size_t ws_size,
                              hipStream_t stream) {
    const float* x    = (const float*)d_in[0];
    const float* W_ih = (const float*)d_in[1];
    const float* W_hh = (const float*)d_in[2];
    const float* b_ih = (const float*)d_in[3];
    const float* b_hh = (const float*)d_in[4];
    const float* Wk   = (const float*)d_in[5];
    const float* bk   = (const float*)d_in[6];
    const float* Wsm  = (const float*)d_in[7];
    const float* bs   = (const float*)d_in[8];
    const float* Wo   = (const float*)d_in[9];
    const float* bo   = (const float*)d_in[10];
    float* out = (float*)d_out;

    const size_t gx_elems  = (size_t)TSTEPS * BATCH * G4H;  // 40,960,000 f32
    const size_t whh_q4_e  = (size_t)50 * 400;              // uint4 (16B)
    const size_t wk_q2_e   = (size_t)50 * 160;              // uint2 (8B)
    const size_t wsm_q_e   = (size_t)400;                   // uint (4B)
    const size_t a_elems   = (size_t)TSTEPS * BATCH * KP;   // u16 each
    const size_t w_elems   = (size_t)2 * WROWS * KP;        // u16
    const size_t need_base = gx_elems * 4 + whh_q4_e * 16 + wk_q2_e * 8 + wsm_q_e * 4;
    const size_t need_mfma = need_base + (2 * a_elems + w_elems) * 2;
    if (ws_size < need_base) return;

    float* gxb = (float*)d_ws;
    uint4* Whh_q4 = (uint4*)(gxb + gx_elems);
    uint2* Wk_q2  = (uint2*)(Whh_q4 + whh_q4_e);
    uint32_t* Wsm_q = (uint32_t*)(Wk_q2 + wk_q2_e);

    {
        int tot = (int)(whh_q4_e + wk_q2_e + wsm_q_e);
        convert_recQ<<<dim3((tot + 255) / 256), dim3(256), 0, stream>>>(
            W_hh, Wk, Wsm, Whh_q4, Wk_q2, Wsm_q);
    }

    if (ws_size >= need_mfma) {
        unsigned short* Ahi = (unsigned short*)(Wsm_q + wsm_q_e);
        unsigned short* Alo = Ahi + a_elems;
        unsigned short* Wpk = Alo + a_elems;
        convert_A<<<dim3(2, TSTEPS * BATCH), dim3(256), 0, stream>>>(x, Ahi, Alo);
        convert_W<<<dim3(2, WROWS, 2), dim3(256), 0, stream>>>(W_ih, Wpk);
        gx_gemm_mfma<<<dim3(7, (TSTEPS * BATCH) / 128), dim3(256), 0, stream>>>(
            Ahi, Alo, Wpk, b_ih, b_hh, gxb);
    } else {
        gx_gemm<<<dim3(G4H / 80, (TSTEPS * BATCH) / 128), dim3(256), 0, stream>>>(
            x, W_ih, b_ih, b_hh, gxb);
    }

    ntm_scan<<<dim3(BATCH / NG), dim3(512), 0, stream>>>(
        gxb, Whh_q4, Wk_q2, bk, Wsm_q, bs, Wo, bo, out);
}